// Round 1
// baseline (4522.224 us; speedup 1.0000x reference)
//
#include <hip/hip_runtime.h>
#include <math.h>

#define NC_   3072
#define NT_   1024
#define NTOK  4096
#define DD    256
#define NH    8
#define HDIM  32
#define NL    2
#define FFD   1024

// ---------------- outcome-token decorator: c = concat(c_ctx,c_tgt) + (w*mask)*y_emb ----
__global__ __launch_bounds__(256) void decorate_kernel(
    const float* __restrict__ c_ctx, const float* __restrict__ c_tgt,
    const float* __restrict__ y_context, const float* __restrict__ exposure_context,
    const float* __restrict__ dec_W1, const float* __restrict__ dec_b1,
    const float* __restrict__ dec_W2, const float* __restrict__ dec_b2,
    const float* __restrict__ log_kappa, float* __restrict__ c)
{
    int row = blockIdx.x, tid = threadIdx.x;
    if (row >= NC_) {
        c[row*DD + tid] = c_tgt[(row-NC_)*DD + tid];
        return;
    }
    __shared__ float tv[DD];
    float y = y_context[row];
    tv[tid] = tanhf(y * dec_W1[tid] + dec_b1[tid]);
    __syncthreads();
    float kappa = log1pf(expf(log_kappa[0]));   // softplus
    float e = exposure_context[row];
    float w = e / (e + kappa);
    float acc = 0.f;
    #pragma unroll 16
    for (int k = 0; k < DD; ++k) acc += tv[k] * dec_W2[k*DD + tid];
    c[row*DD + tid] = c_ctx[row*DD + tid] + w * (acc + dec_b2[tid]);
}

// ---------------- generic fp32 GEMM: C[M][N] = A[M][K] @ B[K][N] + bias, opt relu ----
// block 256 (16x16), 64x64 tile, K-step 16, 4x4 per-thread micro-tile
__global__ __launch_bounds__(256) void gemm_kernel(
    const float* __restrict__ A, const float* __restrict__ B,
    const float* __restrict__ bias, float* __restrict__ C,
    int M, int N, int K, int relu)
{
    __shared__ float As[16][65];   // [k][m], padded
    __shared__ float Bs[16][64];   // [k][n]
    int tid = threadIdx.x;
    int tx = tid & 15, ty = tid >> 4;
    int m0 = blockIdx.y * 64, n0 = blockIdx.x * 64;
    int ar = tid >> 4, ak = tid & 15;   // A-stage: row base, k
    int bk = tid >> 6, bc = tid & 63;   // B-stage: k base, col
    float acc[4][4] = {};
    for (int k0 = 0; k0 < K; k0 += 16) {
        __syncthreads();
        #pragma unroll
        for (int i = 0; i < 4; ++i)
            As[ak][ar + i*16] = A[(m0 + ar + i*16)*K + k0 + ak];
        #pragma unroll
        for (int i = 0; i < 4; ++i)
            Bs[bk + i*4][bc] = B[(k0 + bk + i*4)*N + n0 + bc];
        __syncthreads();
        #pragma unroll
        for (int kk = 0; kk < 16; ++kk) {
            float a[4], b[4];
            #pragma unroll
            for (int i = 0; i < 4; ++i) a[i] = As[kk][ty*4 + i];
            #pragma unroll
            for (int j = 0; j < 4; ++j) b[j] = Bs[kk][tx*4 + j];
            #pragma unroll
            for (int i = 0; i < 4; ++i)
                #pragma unroll
                for (int j = 0; j < 4; ++j)
                    acc[i][j] += a[i] * b[j];
        }
    }
    #pragma unroll
    for (int i = 0; i < 4; ++i) {
        int m = m0 + ty*4 + i;
        #pragma unroll
        for (int j = 0; j < 4; ++j) {
            int nn = n0 + tx*4 + j;
            float v = acc[i][j] + bias[nn];
            if (relu) v = fmaxf(v, 0.f);
            C[m*N + nn] = v;
        }
    }
}

// ---------------- flash attention (fp32), one head per blockIdx.y ----------------
// 32 queries/block (4 waves x 8 q each). Key tiles of 64: each lane owns one key
// row in registers (global, collectively coalesced); V staged in LDS row-major.
// Target queries: keys [0,NC) + explicit self key (structural mask).
__global__ __launch_bounds__(256) void attn_kernel(
    const float* __restrict__ Q, const float* __restrict__ K,
    const float* __restrict__ V, float* __restrict__ O)
{
    __shared__ float Qs[32][32];
    __shared__ float Vs[64][32];
    int tid = threadIdx.x;
    int wid = tid >> 6, lane = tid & 63;
    int h = blockIdx.y;
    int q0 = blockIdx.x * 32;
    const float rscale = 0.1767766952966369f;   // 1/sqrt(32)
    {   // stage Q tile: 32x32
        int r = tid >> 3, c4 = (tid & 7) * 4;
        *(float4*)&Qs[r][c4] = *(const float4*)&Q[(q0 + r)*DD + h*HDIM + c4];
    }
    float m[8], l[8], oacc[8];
    #pragma unroll
    for (int j = 0; j < 8; ++j) { m[j] = -INFINITY; l[j] = 0.f; oacc[j] = 0.f; }
    const int is_tgt = (q0 >= NC_);
    const int nk = is_tgt ? NC_ : NTOK;
    const int dd = lane & 31, half = lane >> 5;

    for (int k0 = 0; k0 < nk; k0 += 64) {
        __syncthreads();
        {   // stage V tile 64x32 (row-major, 2-way bank aliasing = free)
            int u = tid;
            #pragma unroll
            for (int s = 0; s < 2; ++s) {
                int r = u >> 3, c4 = (u & 7) * 4;
                *(float4*)&Vs[r][c4] = *(const float4*)&V[(k0 + r)*DD + h*HDIM + c4];
                u += 256;
            }
        }
        // my key row -> registers (contiguous 128B per lane)
        float4 kreg[8];
        #pragma unroll
        for (int j = 0; j < 8; ++j)
            kreg[j] = *(const float4*)&K[(k0 + lane)*DD + h*HDIM + j*4];
        __syncthreads();
        #pragma unroll
        for (int j = 0; j < 8; ++j) {
            int qr = wid*8 + j;
            float s = 0.f;
            #pragma unroll
            for (int u = 0; u < 8; ++u) {
                float4 qv = *(const float4*)&Qs[qr][u*4];   // wave-uniform: broadcast
                s += qv.x*kreg[u].x + qv.y*kreg[u].y + qv.z*kreg[u].z + qv.w*kreg[u].w;
            }
            s *= rscale;
            float tmax = s;
            #pragma unroll
            for (int off = 1; off < 64; off <<= 1)
                tmax = fmaxf(tmax, __shfl_xor(tmax, off, 64));
            float mn = fmaxf(m[j], tmax);
            float p = expf(s - mn);
            float corr = expf(m[j] - mn);
            float ps = p;
            #pragma unroll
            for (int off = 1; off < 64; off <<= 1)
                ps += __shfl_xor(ps, off, 64);
            l[j] = l[j]*corr + ps;
            float o = oacc[j] * corr;
            #pragma unroll
            for (int jj = 0; jj < 32; ++jj) {
                float pk = __shfl(p, (half << 5) + jj, 64);
                o += pk * Vs[(half << 5) + jj][dd];
            }
            oacc[j] = o;
            m[j] = mn;
        }
    }
    if (is_tgt) {   // self key for target queries
        #pragma unroll
        for (int j = 0; j < 8; ++j) {
            int qr = wid*8 + j;
            int q  = q0 + qr;
            float s = Qs[qr][dd] * K[q*DD + h*HDIM + dd];
            #pragma unroll
            for (int off = 1; off < 32; off <<= 1)
                s += __shfl_xor(s, off, 64);      // both halves independently reduce -> same value
            s *= rscale;
            float mn = fmaxf(m[j], s);
            float p = expf(s - mn);
            float corr = expf(m[j] - mn);
            l[j] = l[j]*corr + p;
            oacc[j] *= corr;
            if (half == 0) oacc[j] += p * V[q*DD + h*HDIM + dd];
            m[j] = mn;
        }
    }
    #pragma unroll
    for (int j = 0; j < 8; ++j) {
        float o = oacc[j] + __shfl_xor(oacc[j], 32, 64);
        if (half == 0) {
            int q = q0 + wid*8 + j;
            O[q*DD + h*HDIM + dd] = o / l[j];
        }
    }
}

// ---------------- layernorm: c = LN(c + delta)*g + b ; wave per row ----------------
__global__ __launch_bounds__(256) void ln_kernel(
    float* __restrict__ c, const float* __restrict__ delta,
    const float* __restrict__ g, const float* __restrict__ b)
{
    int tid = threadIdx.x;
    int wid = tid >> 6, lane = tid & 63;
    int row = blockIdx.x * 4 + wid;
    float4 x  = *(const float4*)&c[row*DD + lane*4];
    float4 dl = *(const float4*)&delta[row*DD + lane*4];
    x.x += dl.x; x.y += dl.y; x.z += dl.z; x.w += dl.w;
    float s = x.x + x.y + x.z + x.w;
    #pragma unroll
    for (int off = 1; off < 64; off <<= 1) s += __shfl_xor(s, off, 64);
    float mean = s * (1.f/DD);
    float dx = x.x-mean, dy = x.y-mean, dz = x.z-mean, dw = x.w-mean;
    float v = dx*dx + dy*dy + dz*dz + dw*dw;
    #pragma unroll
    for (int off = 1; off < 64; off <<= 1) v += __shfl_xor(v, off, 64);
    float rstd = rsqrtf(v*(1.f/DD) + 1e-5f);
    float4 g4 = *(const float4*)&g[lane*4];
    float4 b4 = *(const float4*)&b[lane*4];
    float4 o;
    o.x = dx*rstd*g4.x + b4.x;
    o.y = dy*rstd*g4.y + b4.y;
    o.z = dz*rstd*g4.z + b4.z;
    o.w = dw*rstd*g4.w + b4.w;
    *(float4*)&c[row*DD + lane*4] = o;
}

// ---------------- head: out = exp(c_tgt @ out_W + out_b) * exposure ----------------
__global__ __launch_bounds__(256) void out_kernel(
    const float* __restrict__ c, const float* __restrict__ out_W,
    const float* __restrict__ out_b, const float* __restrict__ exposure_target,
    float* __restrict__ out)
{
    int tid = threadIdx.x;
    int wid = tid >> 6, lane = tid & 63;
    int r = blockIdx.x * 4 + wid;
    float4 cv = *(const float4*)&c[(NC_ + r)*DD + lane*4];
    float4 wv = *(const float4*)&out_W[lane*4];
    float s = cv.x*wv.x + cv.y*wv.y + cv.z*wv.z + cv.w*wv.w;
    #pragma unroll
    for (int off = 1; off < 64; off <<= 1) s += __shfl_xor(s, off, 64);
    if (lane == 0) out[r] = expf(s + out_b[0]) * exposure_target[r];
}

extern "C" void kernel_launch(void* const* d_in, const int* in_sizes, int n_in,
                              void* d_out, int out_size, void* d_ws, size_t ws_size,
                              hipStream_t stream) {
    const float* c_ctx            = (const float*)d_in[0];
    const float* c_tgt            = (const float*)d_in[1];
    const float* y_context        = (const float*)d_in[2];
    const float* exposure_context = (const float*)d_in[3];
    const float* exposure_target  = (const float*)d_in[4];
    const float* dec_W1           = (const float*)d_in[5];
    const float* dec_b1           = (const float*)d_in[6];
    const float* dec_W2           = (const float*)d_in[7];
    const float* dec_b2           = (const float*)d_in[8];
    const float* log_kappa        = (const float*)d_in[9];
    const float* WQ               = (const float*)d_in[10];
    const float* bQ               = (const float*)d_in[11];
    const float* WK               = (const float*)d_in[12];
    const float* bK               = (const float*)d_in[13];
    const float* WV               = (const float*)d_in[14];
    const float* bV               = (const float*)d_in[15];
    const float* WO               = (const float*)d_in[16];
    const float* bO               = (const float*)d_in[17];
    const float* ln1_g            = (const float*)d_in[18];
    const float* ln1_b            = (const float*)d_in[19];
    const float* ln2_g            = (const float*)d_in[20];
    const float* ln2_b            = (const float*)d_in[21];
    const float* ffn_W1           = (const float*)d_in[22];
    const float* ffn_b1           = (const float*)d_in[23];
    const float* ffn_W2           = (const float*)d_in[24];
    const float* ffn_b2           = (const float*)d_in[25];
    const float* out_W            = (const float*)d_in[26];
    const float* out_b            = (const float*)d_in[27];
    float* out = (float*)d_out;

    float* ws = (float*)d_ws;
    float* c  = ws;                    // NTOK*DD
    float* T  = ws + 1*NTOK*DD;        // NTOK*DD
    float* Qb = ws + 2*NTOK*DD;        // NTOK*DD
    float* Kb = ws + 3*NTOK*DD;        // NTOK*DD
    float* Vb = ws + 4*NTOK*DD;        // NTOK*DD
    float* AO = ws + 5*NTOK*DD;        // NTOK*DD
    float* Hd = Qb;                    // NTOK*FFD  (aliases Qb..AO; dead by FFN time)

    decorate_kernel<<<NTOK, 256, 0, stream>>>(c_ctx, c_tgt, y_context, exposure_context,
                                              dec_W1, dec_b1, dec_W2, dec_b2, log_kappa, c);
    for (int l = 0; l < NL; ++l) {
        dim3 gq(DD/64, NTOK/64);
        gemm_kernel<<<gq, 256, 0, stream>>>(c, WQ + l*DD*DD, bQ + l*DD, Qb, NTOK, DD, DD, 0);
        gemm_kernel<<<gq, 256, 0, stream>>>(c, WK + l*DD*DD, bK + l*DD, Kb, NTOK, DD, DD, 0);
        gemm_kernel<<<gq, 256, 0, stream>>>(c, WV + l*DD*DD, bV + l*DD, Vb, NTOK, DD, DD, 0);
        attn_kernel<<<dim3(NTOK/32, NH), 256, 0, stream>>>(Qb, Kb, Vb, AO);
        gemm_kernel<<<gq, 256, 0, stream>>>(AO, WO + l*DD*DD, bO + l*DD, T, NTOK, DD, DD, 0);
        ln_kernel<<<NTOK/4, 256, 0, stream>>>(c, T, ln1_g + l*DD, ln1_b + l*DD);
        gemm_kernel<<<dim3(FFD/64, NTOK/64), 256, 0, stream>>>(c, ffn_W1 + l*DD*FFD, ffn_b1 + l*FFD, Hd, NTOK, FFD, DD, 1);
        gemm_kernel<<<dim3(DD/64, NTOK/64), 256, 0, stream>>>(Hd, ffn_W2 + l*FFD*DD, ffn_b2 + l*DD, T, NTOK, DD, FFD, 0);
        ln_kernel<<<NTOK/4, 256, 0, stream>>>(c, T, ln2_g + l*DD, ln2_b + l*DD);
    }
    out_kernel<<<NT_/4, 256, 0, stream>>>(c, out_W, out_b, exposure_target, out);
}

// Round 2
// 782.278 us; speedup vs baseline: 5.7808x; 5.7808x over previous
//
#include <hip/hip_runtime.h>
#include <hip/hip_bf16.h>
#include <math.h>

#define NC_   3072
#define NT_   1024
#define NTOK  4096
#define DD    256
#define NH    8
#define HDIM  32
#define NL    2
#define FFD   1024

typedef __attribute__((ext_vector_type(8))) short short8;
typedef __attribute__((ext_vector_type(4))) float f32x4;

__device__ inline float bf2f(ushort u) { return __uint_as_float(((unsigned)u) << 16); }
__device__ inline ushort f2bf(float x) {
    __hip_bfloat16 h = __float2bfloat16(x);
    return *reinterpret_cast<ushort*>(&h);
}

// ---------------- outcome-token decorator ----------------
__global__ __launch_bounds__(256) void decorate_kernel(
    const float* __restrict__ c_ctx, const float* __restrict__ c_tgt,
    const float* __restrict__ y_context, const float* __restrict__ exposure_context,
    const float* __restrict__ dec_W1, const float* __restrict__ dec_b1,
    const float* __restrict__ dec_W2, const float* __restrict__ dec_b2,
    const float* __restrict__ log_kappa, float* __restrict__ c)
{
    int row = blockIdx.x, tid = threadIdx.x;
    if (row >= NC_) {
        c[row*DD + tid] = c_tgt[(row-NC_)*DD + tid];
        return;
    }
    __shared__ float tv[DD];
    float y = y_context[row];
    tv[tid] = tanhf(y * dec_W1[tid] + dec_b1[tid]);
    __syncthreads();
    float kappa = log1pf(expf(log_kappa[0]));   // softplus
    float e = exposure_context[row];
    float w = e / (e + kappa);
    float acc = 0.f;
    #pragma unroll 16
    for (int k = 0; k < DD; ++k) acc += tv[k] * dec_W2[k*DD + tid];
    c[row*DD + tid] = c_ctx[row*DD + tid] + w * (acc + dec_b2[tid]);
}

// ---------------- fp32 GEMM: C = A@B + bias, out_mode: 0=f32, 1=bf16, 2=bf16 transposed ----
__global__ __launch_bounds__(256) void gemm_kernel(
    const float* __restrict__ A, const float* __restrict__ B,
    const float* __restrict__ bias, void* __restrict__ Cv,
    int M, int N, int K, int relu, int out_mode)
{
    __shared__ float As[16][65];   // [k][m], padded
    __shared__ float Bs[16][64];   // [k][n]
    int tid = threadIdx.x;
    int tx = tid & 15, ty = tid >> 4;
    int m0 = blockIdx.y * 64, n0 = blockIdx.x * 64;
    int ar = tid >> 4, ak = tid & 15;
    int bk = tid >> 6, bc = tid & 63;
    float acc[4][4] = {};
    for (int k0 = 0; k0 < K; k0 += 16) {
        __syncthreads();
        #pragma unroll
        for (int i = 0; i < 4; ++i)
            As[ak][ar + i*16] = A[(m0 + ar + i*16)*K + k0 + ak];
        #pragma unroll
        for (int i = 0; i < 4; ++i)
            Bs[bk + i*4][bc] = B[(k0 + bk + i*4)*N + n0 + bc];
        __syncthreads();
        #pragma unroll
        for (int kk = 0; kk < 16; ++kk) {
            float a[4], b[4];
            #pragma unroll
            for (int i = 0; i < 4; ++i) a[i] = As[kk][ty*4 + i];
            #pragma unroll
            for (int j = 0; j < 4; ++j) b[j] = Bs[kk][tx*4 + j];
            #pragma unroll
            for (int i = 0; i < 4; ++i)
                #pragma unroll
                for (int j = 0; j < 4; ++j)
                    acc[i][j] += a[i] * b[j];
        }
    }
    #pragma unroll
    for (int i = 0; i < 4; ++i) {
        int m = m0 + ty*4 + i;
        #pragma unroll
        for (int j = 0; j < 4; ++j) {
            int nn = n0 + tx*4 + j;
            float v = acc[i][j] + bias[nn];
            if (relu) v = fmaxf(v, 0.f);
            if (out_mode == 0)      ((float*)Cv)[m*N + nn] = v;
            else if (out_mode == 1) ((ushort*)Cv)[m*N + nn] = f2bf(v);
            else                    ((ushort*)Cv)[(size_t)nn*M + m] = f2bf(v);  // transposed
        }
    }
}

// ---------------- MFMA flash attention (bf16 in, fp32 out) ----------------
// grid (NTOK/64, NH), block 256 = 4 waves. Wave w owns 16 queries.
// QK^T: one mfma_f32_16x16x32_bf16 per 16-key tile (K-dim = HD = 32 exactly).
// P relayout through per-wave XOR-swizzled LDS; PV via mfma, V read from Vt[d][token].
// Target queries: keys [0,NC) + explicit self-key (structural mask, no -inf).
__global__ __launch_bounds__(256) void attn_mfma_kernel(
    const ushort* __restrict__ Q, const ushort* __restrict__ K,
    const ushort* __restrict__ Vt, float* __restrict__ O)
{
    __shared__ char Plds[4][2048];     // per-wave 16x64 bf16, XOR-swizzled
    int tid = threadIdx.x;
    int w = tid >> 6, lane = tid & 63;
    int h = blockIdx.y;
    int q0 = blockIdx.x * 64 + w * 16;
    int col = lane & 15, grp = lane >> 4;
    char* pbase = Plds[w];
    const float rscale = 0.1767766952966369f;   // 1/sqrt(32)

    // Q A-fragment: lane holds Q[q0+col][grp*8 .. +8) of this head (16B contiguous)
    short8 aq = *(const short8*)&Q[(size_t)(q0 + col)*DD + h*HDIM + grp*8];

    f32x4 acc0 = {0.f,0.f,0.f,0.f}, acc1 = {0.f,0.f,0.f,0.f};
    float m[4], l[4];
    #pragma unroll
    for (int r = 0; r < 4; ++r) { m[r] = -INFINITY; l[r] = 0.f; }

    const int is_tgt = (q0 >= NC_);
    const int nk = is_tgt ? NC_ : NTOK;

    for (int kb = 0; kb < nk; kb += 64) {
        // ---- QK^T: 4 tiles of 16 keys ----
        f32x4 s0, s1, s2, s3;
        {
            f32x4 z = {0.f,0.f,0.f,0.f};
            short8 b0 = *(const short8*)&K[(size_t)(kb +  0 + col)*DD + h*HDIM + grp*8];
            short8 b1 = *(const short8*)&K[(size_t)(kb + 16 + col)*DD + h*HDIM + grp*8];
            short8 b2 = *(const short8*)&K[(size_t)(kb + 32 + col)*DD + h*HDIM + grp*8];
            short8 b3 = *(const short8*)&K[(size_t)(kb + 48 + col)*DD + h*HDIM + grp*8];
            s0 = __builtin_amdgcn_mfma_f32_16x16x32_bf16(aq, b0, z, 0, 0, 0);
            s1 = __builtin_amdgcn_mfma_f32_16x16x32_bf16(aq, b1, z, 0, 0, 0);
            s2 = __builtin_amdgcn_mfma_f32_16x16x32_bf16(aq, b2, z, 0, 0, 0);
            s3 = __builtin_amdgcn_mfma_f32_16x16x32_bf16(aq, b3, z, 0, 0, 0);
        }
        // ---- online softmax per row (row = grp*4 + r, cols = t*16 + col) ----
        #pragma unroll
        for (int r = 0; r < 4; ++r) {
            float v0 = s0[r]*rscale, v1 = s1[r]*rscale, v2 = s2[r]*rscale, v3 = s3[r]*rscale;
            float mx = fmaxf(fmaxf(v0, v1), fmaxf(v2, v3));
            #pragma unroll
            for (int off = 1; off < 16; off <<= 1)
                mx = fmaxf(mx, __shfl_xor(mx, off, 64));
            float mnew = fmaxf(m[r], mx);
            float corr = expf(m[r] - mnew);
            float p0 = expf(v0 - mnew), p1 = expf(v1 - mnew);
            float p2 = expf(v2 - mnew), p3 = expf(v3 - mnew);
            float ps = p0 + p1 + p2 + p3;
            #pragma unroll
            for (int off = 1; off < 16; off <<= 1)
                ps += __shfl_xor(ps, off, 64);
            l[r] = l[r]*corr + ps;
            m[r] = mnew;
            acc0[r] *= corr; acc1[r] *= corr;
            int row = grp*4 + r;
            int swz = (row & 7) << 4;
            int rb  = row * 128;
            *(ushort*)(pbase + ((rb + (     col)*2) ^ swz)) = f2bf(p0);
            *(ushort*)(pbase + ((rb + (16 + col)*2) ^ swz)) = f2bf(p1);
            *(ushort*)(pbase + ((rb + (32 + col)*2) ^ swz)) = f2bf(p2);
            *(ushort*)(pbase + ((rb + (48 + col)*2) ^ swz)) = f2bf(p3);
        }
        // ---- PV: O[16q][32d] += P[16q][64k] * V[64k][32d] (2 k-chunks of 32) ----
        #pragma unroll
        for (int s2k = 0; s2k < 2; ++s2k) {
            int row = col;   // A-frag row = lane&15
            int off = (row*128 + s2k*64 + grp*16) ^ ((row & 7) << 4);
            short8 pa = *(const short8*)(pbase + off);
            short8 bv0 = *(const short8*)&Vt[(size_t)(h*HDIM +      col)*NTOK + kb + s2k*32 + grp*8];
            short8 bv1 = *(const short8*)&Vt[(size_t)(h*HDIM + 16 + col)*NTOK + kb + s2k*32 + grp*8];
            acc0 = __builtin_amdgcn_mfma_f32_16x16x32_bf16(pa, bv0, acc0, 0, 0, 0);
            acc1 = __builtin_amdgcn_mfma_f32_16x16x32_bf16(pa, bv1, acc1, 0, 0, 0);
        }
    }

    if (is_tgt) {   // self-key for target queries
        #pragma unroll
        for (int r = 0; r < 4; ++r) {
            int q = q0 + grp*4 + r;
            float dot = 0.f;
            #pragma unroll
            for (int u8 = 0; u8 < 4; ++u8) {
                short8 qv = *(const short8*)&Q[(size_t)q*DD + h*HDIM + u8*8];
                short8 kv = *(const short8*)&K[(size_t)q*DD + h*HDIM + u8*8];
                #pragma unroll
                for (int e = 0; e < 8; ++e)
                    dot += bf2f((ushort)qv[e]) * bf2f((ushort)kv[e]);
            }
            float s = dot * rscale;
            float mnew = fmaxf(m[r], s);
            float corr = expf(m[r] - mnew);
            float p = expf(s - mnew);
            l[r] = l[r]*corr + p;
            m[r] = mnew;
            acc0[r] = acc0[r]*corr + p * bf2f(Vt[(size_t)(h*HDIM +      col)*NTOK + q]);
            acc1[r] = acc1[r]*corr + p * bf2f(Vt[(size_t)(h*HDIM + 16 + col)*NTOK + q]);
        }
    }

    #pragma unroll
    for (int r = 0; r < 4; ++r) {
        int q = q0 + grp*4 + r;
        float inv = 1.f / l[r];
        O[(size_t)q*DD + h*HDIM +      col] = acc0[r] * inv;
        O[(size_t)q*DD + h*HDIM + 16 + col] = acc1[r] * inv;
    }
}

// ---------------- layernorm: c = LN(c + delta)*g + b ; wave per row ----------------
__global__ __launch_bounds__(256) void ln_kernel(
    float* __restrict__ c, const float* __restrict__ delta,
    const float* __restrict__ g, const float* __restrict__ b)
{
    int tid = threadIdx.x;
    int wid = tid >> 6, lane = tid & 63;
    int row = blockIdx.x * 4 + wid;
    float4 x  = *(const float4*)&c[row*DD + lane*4];
    float4 dl = *(const float4*)&delta[row*DD + lane*4];
    x.x += dl.x; x.y += dl.y; x.z += dl.z; x.w += dl.w;
    float s = x.x + x.y + x.z + x.w;
    #pragma unroll
    for (int off = 1; off < 64; off <<= 1) s += __shfl_xor(s, off, 64);
    float mean = s * (1.f/DD);
    float dx = x.x-mean, dy = x.y-mean, dz = x.z-mean, dw = x.w-mean;
    float v = dx*dx + dy*dy + dz*dz + dw*dw;
    #pragma unroll
    for (int off = 1; off < 64; off <<= 1) v += __shfl_xor(v, off, 64);
    float rstd = rsqrtf(v*(1.f/DD) + 1e-5f);
    float4 g4 = *(const float4*)&g[lane*4];
    float4 b4 = *(const float4*)&b[lane*4];
    float4 o;
    o.x = dx*rstd*g4.x + b4.x;
    o.y = dy*rstd*g4.y + b4.y;
    o.z = dz*rstd*g4.z + b4.z;
    o.w = dw*rstd*g4.w + b4.w;
    *(float4*)&c[row*DD + lane*4] = o;
}

// ---------------- head: out = exp(c_tgt @ out_W + out_b) * exposure ----------------
__global__ __launch_bounds__(256) void out_kernel(
    const float* __restrict__ c, const float* __restrict__ out_W,
    const float* __restrict__ out_b, const float* __restrict__ exposure_target,
    float* __restrict__ out)
{
    int tid = threadIdx.x;
    int wid = tid >> 6, lane = tid & 63;
    int r = blockIdx.x * 4 + wid;
    float4 cv = *(const float4*)&c[(NC_ + r)*DD + lane*4];
    float4 wv = *(const float4*)&out_W[lane*4];
    float s = cv.x*wv.x + cv.y*wv.y + cv.z*wv.z + cv.w*wv.w;
    #pragma unroll
    for (int off = 1; off < 64; off <<= 1) s += __shfl_xor(s, off, 64);
    if (lane == 0) out[r] = expf(s + out_b[0]) * exposure_target[r];
}

extern "C" void kernel_launch(void* const* d_in, const int* in_sizes, int n_in,
                              void* d_out, int out_size, void* d_ws, size_t ws_size,
                              hipStream_t stream) {
    const float* c_ctx            = (const float*)d_in[0];
    const float* c_tgt            = (const float*)d_in[1];
    const float* y_context        = (const float*)d_in[2];
    const float* exposure_context = (const float*)d_in[3];
    const float* exposure_target  = (const float*)d_in[4];
    const float* dec_W1           = (const float*)d_in[5];
    const float* dec_b1           = (const float*)d_in[6];
    const float* dec_W2           = (const float*)d_in[7];
    const float* dec_b2           = (const float*)d_in[8];
    const float* log_kappa        = (const float*)d_in[9];
    const float* WQ               = (const float*)d_in[10];
    const float* bQ               = (const float*)d_in[11];
    const float* WK               = (const float*)d_in[12];
    const float* bK               = (const float*)d_in[13];
    const float* WV               = (const float*)d_in[14];
    const float* bV               = (const float*)d_in[15];
    const float* WO               = (const float*)d_in[16];
    const float* bO               = (const float*)d_in[17];
    const float* ln1_g            = (const float*)d_in[18];
    const float* ln1_b            = (const float*)d_in[19];
    const float* ln2_g            = (const float*)d_in[20];
    const float* ln2_b            = (const float*)d_in[21];
    const float* ffn_W1           = (const float*)d_in[22];
    const float* ffn_b1           = (const float*)d_in[23];
    const float* ffn_W2           = (const float*)d_in[24];
    const float* ffn_b2           = (const float*)d_in[25];
    const float* out_W            = (const float*)d_in[26];
    const float* out_b            = (const float*)d_in[27];
    float* out = (float*)d_out;

    float* ws = (float*)d_ws;
    float* c   = ws;                      // NTOK*DD f32
    float* T   = ws + 1*NTOK*DD;          // NTOK*DD f32
    ushort* Qb = (ushort*)(ws + 2*NTOK*DD);   // NTOK*DD bf16
    ushort* Kb = (ushort*)(ws + 3*NTOK*DD);   // NTOK*DD bf16
    ushort* Vt = (ushort*)(ws + 4*NTOK*DD);   // DD*NTOK bf16 (transposed)
    float* AO  = ws + 5*NTOK*DD;          // NTOK*DD f32
    float* Hd  = ws + 2*NTOK*DD;          // NTOK*FFD f32 (aliases Qb..AO; dead by FFN time)

    decorate_kernel<<<NTOK, 256, 0, stream>>>(c_ctx, c_tgt, y_context, exposure_context,
                                              dec_W1, dec_b1, dec_W2, dec_b2, log_kappa, c);
    for (int l = 0; l < NL; ++l) {
        dim3 gq(DD/64, NTOK/64);
        gemm_kernel<<<gq, 256, 0, stream>>>(c, WQ + l*DD*DD, bQ + l*DD, Qb, NTOK, DD, DD, 0, 1);
        gemm_kernel<<<gq, 256, 0, stream>>>(c, WK + l*DD*DD, bK + l*DD, Kb, NTOK, DD, DD, 0, 1);
        gemm_kernel<<<gq, 256, 0, stream>>>(c, WV + l*DD*DD, bV + l*DD, Vt, NTOK, DD, DD, 0, 2);
        attn_mfma_kernel<<<dim3(NTOK/64, NH), 256, 0, stream>>>(Qb, Kb, Vt, AO);
        gemm_kernel<<<gq, 256, 0, stream>>>(AO, WO + l*DD*DD, bO + l*DD, T, NTOK, DD, DD, 0, 0);
        ln_kernel<<<NTOK/4, 256, 0, stream>>>(c, T, ln1_g + l*DD, ln1_b + l*DD);
        gemm_kernel<<<dim3(FFD/64, NTOK/64), 256, 0, stream>>>(c, ffn_W1 + l*DD*FFD, ffn_b1 + l*FFD, Hd, NTOK, FFD, DD, 1, 0);
        gemm_kernel<<<dim3(DD/64, NTOK/64), 256, 0, stream>>>(Hd, ffn_W2 + l*FFD*DD, ffn_b2 + l*DD, T, NTOK, DD, FFD, 0, 0);
        ln_kernel<<<NTOK/4, 256, 0, stream>>>(c, T, ln2_g + l*DD, ln2_b + l*DD);
    }
    out_kernel<<<NT_/4, 256, 0, stream>>>(c, out_W, out_b, exposure_target, out);
}

// Round 3
// 361.976 us; speedup vs baseline: 12.4932x; 2.1611x over previous
//
#include <hip/hip_runtime.h>
#include <hip/hip_bf16.h>
#include <math.h>

#define NC_   3072
#define NT_   1024
#define NTOK  4096
#define DD    256
#define NH    8
#define HDIM  32
#define NL    2
#define FFD   1024

typedef __attribute__((ext_vector_type(8))) short short8;
typedef __attribute__((ext_vector_type(4))) float f32x4;

#if __has_builtin(__builtin_amdgcn_exp2f)
#define EXP2(x) __builtin_amdgcn_exp2f(x)
#else
#define EXP2(x) exp2f(x)
#endif

__device__ inline float bf2f(ushort u) { return __uint_as_float(((unsigned)u) << 16); }
__device__ inline ushort f2bf(float x) {
    __hip_bfloat16 h = __float2bfloat16(x);
    return *reinterpret_cast<ushort*>(&h);
}
__device__ inline void gload16(const void* g, void* l) {
    __builtin_amdgcn_global_load_lds(
        (const __attribute__((address_space(1))) void*)g,
        (__attribute__((address_space(3))) void*)l, 16, 0, 0);
}

// ---------------- weight convert: fp32 [K][N] -> bf16 transposed [N][K], + bQK concat ----
// packed per-layer region (elements): WQKt 131072 | WVt 65536 | WOt 65536 | W1t 262144 | W2t 262144
__global__ __launch_bounds__(256) void convert_kernel(
    const float* __restrict__ WQ, const float* __restrict__ WK,
    const float* __restrict__ WV, const float* __restrict__ WO,
    const float* __restrict__ W1, const float* __restrict__ W2,
    const float* __restrict__ bQ, const float* __restrict__ bK,
    ushort* __restrict__ wbf, float* __restrict__ bqk)
{
    int l = blockIdx.y;
    int idx = blockIdx.x * 256 + threadIdx.x;
    if (idx >= 786432 + 512) return;
    if (idx >= 786432) {
        int i = idx - 786432;
        bqk[l*512 + i] = (i < 256) ? bQ[l*256 + i] : bK[l*256 + (i - 256)];
        return;
    }
    float v;
    if (idx < 131072) {                 // WQKt[512][256]
        int n = idx >> 8, k = idx & 255;
        v = (n < 256) ? WQ[(size_t)(l*256 + k)*256 + n] : WK[(size_t)(l*256 + k)*256 + (n-256)];
    } else if (idx < 196608) {          // WVt[256][256]
        int i = idx - 131072, n = i >> 8, k = i & 255;
        v = WV[(size_t)(l*256 + k)*256 + n];
    } else if (idx < 262144) {          // WOt[256][256]
        int i = idx - 196608, n = i >> 8, k = i & 255;
        v = WO[(size_t)(l*256 + k)*256 + n];
    } else if (idx < 524288) {          // W1t[1024][256]
        int i = idx - 262144, n = i >> 8, k = i & 255;
        v = W1[(size_t)(l*256 + k)*1024 + n];
    } else {                            // W2t[256][1024]
        int i = idx - 524288, n = i >> 10, k = i & 1023;
        v = W2[(size_t)(l*1024 + k)*256 + n];
    }
    wbf[(size_t)l*786432 + idx] = f2bf(v);
}

// ---------------- outcome-token decorator (f32 out + bf16 copy) ----------------
__global__ __launch_bounds__(256) void decorate_kernel(
    const float* __restrict__ c_ctx, const float* __restrict__ c_tgt,
    const float* __restrict__ y_context, const float* __restrict__ exposure_context,
    const float* __restrict__ dec_W1, const float* __restrict__ dec_b1,
    const float* __restrict__ dec_W2, const float* __restrict__ dec_b2,
    const float* __restrict__ log_kappa, float* __restrict__ c, ushort* __restrict__ cbf)
{
    int row = blockIdx.x, tid = threadIdx.x;
    if (row >= NC_) {
        float v = c_tgt[(size_t)(row-NC_)*DD + tid];
        c[(size_t)row*DD + tid] = v;
        cbf[(size_t)row*DD + tid] = f2bf(v);
        return;
    }
    __shared__ float tv[DD];
    float y = y_context[row];
    tv[tid] = tanhf(y * dec_W1[tid] + dec_b1[tid]);
    __syncthreads();
    float kappa = log1pf(expf(log_kappa[0]));   // softplus
    float e = exposure_context[row];
    float w = e / (e + kappa);
    float acc = 0.f;
    #pragma unroll 16
    for (int k = 0; k < DD; ++k) acc += tv[k] * dec_W2[k*DD + tid];
    float v = c_ctx[(size_t)row*DD + tid] + w * (acc + dec_b2[tid]);
    c[(size_t)row*DD + tid] = v;
    cbf[(size_t)row*DD + tid] = f2bf(v);
}

// ---------------- bf16 MFMA GEMM: C[M][N] = A[M][K] @ Bt[N][K]^T + bias ----------------
// 64x64 tile, BK=64, 4 waves (2x2 of 32x32), global_load_lds w/ pre-swizzled source.
// mode: 0=f32, 1=bf16, 2=bf16 transposed (Ct[N][M]), 3=bf16+relu
__global__ __launch_bounds__(256) void gemm_bf(
    const ushort* __restrict__ A, const ushort* __restrict__ Bt,
    const float* __restrict__ bias, void* __restrict__ Cv,
    int M, int N, int K, int mode)
{
    __shared__ ushort As[64*64];   // row-major [64 m][64 k], XOR-swizzled: byte ^= (row&7)<<4
    __shared__ ushort Bs[64*64];   // [64 n][64 k], same swizzle
    int tid = threadIdx.x, lane = tid & 63, w = tid >> 6;
    int wm = w >> 1, wn = w & 1;
    int m0 = blockIdx.y * 64, n0 = blockIdx.x * 64;
    int col = lane & 15, grp = lane >> 4;
    f32x4 acc[2][2] = {};

    for (int k0 = 0; k0 < K; k0 += 64) {
        __syncthreads();
        #pragma unroll
        for (int s = 0; s < 2; ++s) {
            int i = tid + s*256;                 // chunk index 0..511
            int r = i >> 3, j = i & 7;
            int kb = (j*16) ^ ((r & 7) << 4);    // pre-swizzled source byte offset in row
            gload16((const char*)(A  + (size_t)(m0 + r)*K + k0) + kb,
                    (char*)As + s*4096 + w*1024);
            gload16((const char*)(Bt + (size_t)(n0 + r)*K + k0) + kb,
                    (char*)Bs + s*4096 + w*1024);
        }
        __syncthreads();
        #pragma unroll
        for (int kk = 0; kk < 64; kk += 32) {
            short8 a[2], b[2];
            #pragma unroll
            for (int f = 0; f < 2; ++f) {
                int ra = wm*32 + f*16 + col;
                a[f] = *(const short8*)((char*)As + ra*128 + (((kk + grp*8)*2) ^ ((ra & 7) << 4)));
                int rb = wn*32 + f*16 + col;
                b[f] = *(const short8*)((char*)Bs + rb*128 + (((kk + grp*8)*2) ^ ((rb & 7) << 4)));
            }
            #pragma unroll
            for (int fm = 0; fm < 2; ++fm)
                #pragma unroll
                for (int fn = 0; fn < 2; ++fn)
                    acc[fm][fn] = __builtin_amdgcn_mfma_f32_16x16x32_bf16(a[fm], b[fn], acc[fm][fn], 0, 0, 0);
        }
    }
    #pragma unroll
    for (int fm = 0; fm < 2; ++fm) {
        #pragma unroll
        for (int fn = 0; fn < 2; ++fn) {
            int ncol = n0 + wn*32 + fn*16 + col;
            int mbase = m0 + wm*32 + fm*16 + grp*4;
            float bs = bias[ncol];
            if (mode == 2) {
                ushort4 u;
                u.x = f2bf(acc[fm][fn][0] + bs); u.y = f2bf(acc[fm][fn][1] + bs);
                u.z = f2bf(acc[fm][fn][2] + bs); u.w = f2bf(acc[fm][fn][3] + bs);
                *(ushort4*)((ushort*)Cv + (size_t)ncol*M + mbase) = u;
            } else {
                #pragma unroll
                for (int r = 0; r < 4; ++r) {
                    float v = acc[fm][fn][r] + bs;
                    if (mode == 3) v = fmaxf(v, 0.f);
                    if (mode == 0) ((float*)Cv)[(size_t)(mbase + r)*N + ncol] = v;
                    else           ((ushort*)Cv)[(size_t)(mbase + r)*N + ncol] = f2bf(v);
                }
            }
        }
    }
}

// ---------------- swapped-operand MFMA flash attention ----------------
// grid (NTOK/64, NH), 4 waves x 16 queries. S^T = mfma(K,Q): lane owns 16 keys of ONE
// query -> in-lane softmax reduce (+2 shfl for cross-group max / final l).
// P via wave-private XOR-swizzled LDS; PV: O^T = mfma(V^T, P). Output bf16.
__global__ __launch_bounds__(256) void attn_kernel(
    const ushort* __restrict__ QK, const ushort* __restrict__ Vt,
    ushort* __restrict__ AO)
{
    __shared__ ushort P_lds[4][16*64];
    int tid = threadIdx.x;
    int w = tid >> 6, lane = tid & 63;
    int q = lane & 15, g = lane >> 4;
    int h = blockIdx.y;
    int q0 = blockIdx.x * 64 + w * 16;
    char* pb = (char*)P_lds[w];
    const float C = 0.25503483f;    // log2(e)/sqrt(32)
    const int swz = (q & 7) << 4;

    // Q B-frag: lane holds Q[q0+q][hd = g*8..+8]
    short8 bq = *(const short8*)&QK[(size_t)(q0 + q)*512 + h*HDIM + g*8];

    f32x4 acc0 = {0.f,0.f,0.f,0.f}, acc1 = {0.f,0.f,0.f,0.f};
    float mC = -INFINITY, lsum = 0.f;

    const int is_tgt = (q0 >= NC_);
    const int nk = is_tgt ? NC_ : NTOK;
    const ushort* kbase = QK + (size_t)q*512 + 256 + h*HDIM + g*8;   // key row = q (lane&15)
    const ushort* vb0 = Vt + (size_t)(h*HDIM + q)*NTOK + g*8;        // V^T row d = q
    const ushort* vb1 = vb0 + (size_t)16*NTOK;

    for (int kb = 0; kb < nk; kb += 64) {
        f32x4 st[4];
        {
            f32x4 z = {0.f,0.f,0.f,0.f};
            #pragma unroll
            for (int t = 0; t < 4; ++t) {
                short8 ka = *(const short8*)(kbase + (size_t)(kb + 16*t)*512);
                st[t] = __builtin_amdgcn_mfma_f32_16x16x32_bf16(ka, bq, z, 0, 0, 0);
            }
        }
        // in-lane max tree over 16 + cross-group (2 shfl)
        float x0 = fmaxf(fmaxf(st[0][0], st[0][1]), fmaxf(st[0][2], st[0][3]));
        float x1 = fmaxf(fmaxf(st[1][0], st[1][1]), fmaxf(st[1][2], st[1][3]));
        float x2 = fmaxf(fmaxf(st[2][0], st[2][1]), fmaxf(st[2][2], st[2][3]));
        float x3 = fmaxf(fmaxf(st[3][0], st[3][1]), fmaxf(st[3][2], st[3][3]));
        float mx = fmaxf(fmaxf(x0, x1), fmaxf(x2, x3));
        mx = fmaxf(mx, __shfl_xor(mx, 16, 64));
        mx = fmaxf(mx, __shfl_xor(mx, 32, 64));
        float mCn = fmaxf(mC, mx * C);
        float corr = EXP2(mC - mCn);
        mC = mCn;
        acc0 *= corr; acc1 *= corr; lsum *= corr;
        float p[16];
        #pragma unroll
        for (int t = 0; t < 4; ++t)
            #pragma unroll
            for (int r = 0; r < 4; ++r)
                p[t*4 + r] = EXP2(st[t][r]*C - mC);
        float s01 = (p[0]+p[1]) + (p[2]+p[3]),  s23 = (p[4]+p[5]) + (p[6]+p[7]);
        float s45 = (p[8]+p[9]) + (p[10]+p[11]), s67 = (p[12]+p[13]) + (p[14]+p[15]);
        lsum += (s01 + s23) + (s45 + s67);      // per-lane partial; reduced at end
        // pack & write P (keys 16t+4g..+3 of query q), b64 swizzled
        #pragma unroll
        for (int t = 0; t < 4; ++t) {
            uint2 dd;
            dd.x = (uint)f2bf(p[t*4+0]) | ((uint)f2bf(p[t*4+1]) << 16);
            dd.y = (uint)f2bf(p[t*4+2]) | ((uint)f2bf(p[t*4+3]) << 16);
            *(uint2*)(pb + q*128 + (((16*t + 4*g)*2) ^ swz)) = dd;
        }
        // PV: acc[d][q] += V^T[d][k] * P[k][q], 2 chunks of K=32
        #pragma unroll
        for (int c = 0; c < 2; ++c) {
            short8 pfrag = *(const short8*)(pb + q*128 + (((32*c + 8*g)*2) ^ swz));
            short8 va0 = *(const short8*)(vb0 + kb + 32*c);
            short8 va1 = *(const short8*)(vb1 + kb + 32*c);
            acc0 = __builtin_amdgcn_mfma_f32_16x16x32_bf16(va0, pfrag, acc0, 0, 0, 0);
            acc1 = __builtin_amdgcn_mfma_f32_16x16x32_bf16(va1, pfrag, acc1, 0, 0, 0);
        }
    }

    if (is_tgt) {   // self-key (structural mask: targets see ctx + self only)
        int qg = q0 + q;
        short8 kv = *(const short8*)&QK[(size_t)qg*512 + 256 + h*HDIM + g*8];
        float d8 = 0.f;
        #pragma unroll
        for (int e = 0; e < 8; ++e) d8 += bf2f((ushort)bq[e]) * bf2f((ushort)kv[e]);
        d8 += __shfl_xor(d8, 16, 64);
        d8 += __shfl_xor(d8, 32, 64);
        float sC = d8 * C;
        float mCn = fmaxf(mC, sC);
        float corr = EXP2(mC - mCn);
        float pp = EXP2(sC - mCn);
        mC = mCn;
        lsum = lsum*corr + ((g == 0) ? pp : 0.f);   // count self-p once across groups
        acc0 *= corr; acc1 *= corr;
        #pragma unroll
        for (int r = 0; r < 4; ++r) {
            acc0[r] += pp * bf2f(Vt[(size_t)(h*HDIM + g*4 + r)*NTOK + qg]);
            acc1[r] += pp * bf2f(Vt[(size_t)(h*HDIM + 16 + g*4 + r)*NTOK + qg]);
        }
    }

    lsum += __shfl_xor(lsum, 16, 64);
    lsum += __shfl_xor(lsum, 32, 64);
    float inv = 1.f / lsum;
    ushort* dst = AO + (size_t)(q0 + q)*DD + h*HDIM;
    ushort4 o0, o1;
    o0.x = f2bf(acc0[0]*inv); o0.y = f2bf(acc0[1]*inv);
    o0.z = f2bf(acc0[2]*inv); o0.w = f2bf(acc0[3]*inv);
    o1.x = f2bf(acc1[0]*inv); o1.y = f2bf(acc1[1]*inv);
    o1.z = f2bf(acc1[2]*inv); o1.w = f2bf(acc1[3]*inv);
    *(ushort4*)(dst + g*4) = o0;
    *(ushort4*)(dst + 16 + g*4) = o1;
}

// ---------------- layernorm: c = LN(c + delta)*g + b ; + bf16 copy ----------------
__global__ __launch_bounds__(256) void ln_kernel(
    float* __restrict__ c, const float* __restrict__ delta,
    const float* __restrict__ g, const float* __restrict__ b, ushort* __restrict__ cbf)
{
    int tid = threadIdx.x;
    int wid = tid >> 6, lane = tid & 63;
    int row = blockIdx.x * 4 + wid;
    float4 x  = *(const float4*)&c[(size_t)row*DD + lane*4];
    float4 dl = *(const float4*)&delta[(size_t)row*DD + lane*4];
    x.x += dl.x; x.y += dl.y; x.z += dl.z; x.w += dl.w;
    float s = x.x + x.y + x.z + x.w;
    #pragma unroll
    for (int off = 1; off < 64; off <<= 1) s += __shfl_xor(s, off, 64);
    float mean = s * (1.f/DD);
    float dx = x.x-mean, dy = x.y-mean, dz = x.z-mean, dw = x.w-mean;
    float v = dx*dx + dy*dy + dz*dz + dw*dw;
    #pragma unroll
    for (int off = 1; off < 64; off <<= 1) v += __shfl_xor(v, off, 64);
    float rstd = rsqrtf(v*(1.f/DD) + 1e-5f);
    float4 g4 = *(const float4*)&g[lane*4];
    float4 b4 = *(const float4*)&b[lane*4];
    float4 o;
    o.x = dx*rstd*g4.x + b4.x;
    o.y = dy*rstd*g4.y + b4.y;
    o.z = dz*rstd*g4.z + b4.z;
    o.w = dw*rstd*g4.w + b4.w;
    *(float4*)&c[(size_t)row*DD + lane*4] = o;
    ushort4 u;
    u.x = f2bf(o.x); u.y = f2bf(o.y); u.z = f2bf(o.z); u.w = f2bf(o.w);
    *(ushort4*)&cbf[(size_t)row*DD + lane*4] = u;
}

// ---------------- head: out = exp(c_tgt @ out_W + out_b) * exposure ----------------
__global__ __launch_bounds__(256) void out_kernel(
    const float* __restrict__ c, const float* __restrict__ out_W,
    const float* __restrict__ out_b, const float* __restrict__ exposure_target,
    float* __restrict__ out)
{
    int tid = threadIdx.x;
    int wid = tid >> 6, lane = tid & 63;
    int r = blockIdx.x * 4 + wid;
    float4 cv = *(const float4*)&c[(size_t)(NC_ + r)*DD + lane*4];
    float4 wv = *(const float4*)&out_W[lane*4];
    float s = cv.x*wv.x + cv.y*wv.y + cv.z*wv.z + cv.w*wv.w;
    #pragma unroll
    for (int off = 1; off < 64; off <<= 1) s += __shfl_xor(s, off, 64);
    if (lane == 0) out[r] = expf(s + out_b[0]) * exposure_target[r];
}

extern "C" void kernel_launch(void* const* d_in, const int* in_sizes, int n_in,
                              void* d_out, int out_size, void* d_ws, size_t ws_size,
                              hipStream_t stream) {
    const float* c_ctx            = (const float*)d_in[0];
    const float* c_tgt            = (const float*)d_in[1];
    const float* y_context        = (const float*)d_in[2];
    const float* exposure_context = (const float*)d_in[3];
    const float* exposure_target  = (const float*)d_in[4];
    const float* dec_W1           = (const float*)d_in[5];
    const float* dec_b1           = (const float*)d_in[6];
    const float* dec_W2           = (const float*)d_in[7];
    const float* dec_b2           = (const float*)d_in[8];
    const float* log_kappa        = (const float*)d_in[9];
    const float* WQ               = (const float*)d_in[10];
    const float* bQ               = (const float*)d_in[11];
    const float* WK               = (const float*)d_in[12];
    const float* bK               = (const float*)d_in[13];
    const float* WV               = (const float*)d_in[14];
    const float* bV               = (const float*)d_in[15];
    const float* WO               = (const float*)d_in[16];
    const float* bO               = (const float*)d_in[17];
    const float* ln1_g            = (const float*)d_in[18];
    const float* ln1_b            = (const float*)d_in[19];
    const float* ln2_g            = (const float*)d_in[20];
    const float* ln2_b            = (const float*)d_in[21];
    const float* ffn_W1           = (const float*)d_in[22];
    const float* ffn_b1           = (const float*)d_in[23];
    const float* ffn_W2           = (const float*)d_in[24];
    const float* ffn_b2           = (const float*)d_in[25];
    const float* out_W            = (const float*)d_in[26];
    const float* out_b            = (const float*)d_in[27];
    float* out = (float*)d_out;

    float* ws = (float*)d_ws;
    float*  c    = ws;                          // 4096*256 f32
    float*  T    = ws + 1048576;                // 4096*256 f32
    ushort* ub   = (ushort*)(ws + 2097152);
    ushort* c_bf = ub;                          // 4096*256 bf16
    ushort* QKb  = ub + 1048576;                // 4096*512 bf16
    ushort* Vt   = ub + 3145728;                // 256*4096 bf16 (V transposed)
    ushort* AO   = ub + 4194304;                // 4096*256 bf16
    ushort* wbf  = ub + 5242880;                // 2*786432 bf16 weights
    float*  bqk  = (float*)(ub + 6815744);      // 2*512 f32
    ushort* Hd   = QKb;                         // 4096*1024 bf16, aliases QKb+Vt+AO (dead then)

    convert_kernel<<<dim3(3074, 2), 256, 0, stream>>>(WQ, WK, WV, WO, ffn_W1, ffn_W2,
                                                      bQ, bK, wbf, bqk);
    decorate_kernel<<<NTOK, 256, 0, stream>>>(c_ctx, c_tgt, y_context, exposure_context,
                                              dec_W1, dec_b1, dec_W2, dec_b2, log_kappa, c, c_bf);
    for (int l = 0; l < NL; ++l) {
        ushort* wl = wbf + (size_t)l*786432;
        gemm_bf<<<dim3(8, 64),  256, 0, stream>>>(c_bf, wl,          bqk + l*512,    QKb, NTOK, 512, DD, 1);
        gemm_bf<<<dim3(4, 64),  256, 0, stream>>>(c_bf, wl + 131072, bV + l*DD,      Vt,  NTOK, DD, DD, 2);
        attn_kernel<<<dim3(NTOK/64, NH), 256, 0, stream>>>(QKb, Vt, AO);
        gemm_bf<<<dim3(4, 64),  256, 0, stream>>>(AO,   wl + 196608, bO + l*DD,      T,   NTOK, DD, DD, 0);
        ln_kernel<<<NTOK/4, 256, 0, stream>>>(c, T, ln1_g + l*DD, ln1_b + l*DD, c_bf);
        gemm_bf<<<dim3(16, 64), 256, 0, stream>>>(c_bf, wl + 262144, ffn_b1 + l*FFD, Hd,  NTOK, FFD, DD, 3);
        gemm_bf<<<dim3(4, 64),  256, 0, stream>>>(Hd,   wl + 524288, ffn_b2 + l*DD,  T,   NTOK, DD, FFD, 0);
        ln_kernel<<<NTOK/4, 256, 0, stream>>>(c, T, ln2_g + l*DD, ln2_b + l*DD, c_bf);
    }
    out_kernel<<<NT_/4, 256, 0, stream>>>(c, out_W, out_b, exposure_target, out);
}

// Round 4
// 358.835 us; speedup vs baseline: 12.6025x; 1.0088x over previous
//
#include <hip/hip_runtime.h>
#include <hip/hip_bf16.h>
#include <math.h>

#define NC_   3072
#define NT_   1024
#define NTOK  4096
#define DD    256
#define NH    8
#define HDIM  32
#define NL    2
#define FFD   1024

typedef __attribute__((ext_vector_type(8))) short short8;
typedef __attribute__((ext_vector_type(4))) float f32x4;

#if __has_builtin(__builtin_amdgcn_exp2f)
#define EXP2(x) __builtin_amdgcn_exp2f(x)
#else
#define EXP2(x) exp2f(x)
#endif

__device__ inline float bf2f(ushort u) { return __uint_as_float(((unsigned)u) << 16); }
__device__ inline ushort f2bf(float x) {
    __hip_bfloat16 h = __float2bfloat16(x);
    return *reinterpret_cast<ushort*>(&h);
}
__device__ inline void gload16(const void* g, void* l) {
    __builtin_amdgcn_global_load_lds(
        (const __attribute__((address_space(1))) void*)g,
        (__attribute__((address_space(3))) void*)l, 16, 0, 0);
}

// ---------------- weight convert: fp32 [K][N] -> bf16 transposed [N][K], + bQKV concat ----
// packed per-layer (elements): WQKVt[768][256] 0..196607 | WOt 196608 | W1t 262144 | W2t 524288
__global__ __launch_bounds__(256) void convert_kernel(
    const float* __restrict__ WQ, const float* __restrict__ WK,
    const float* __restrict__ WV, const float* __restrict__ WO,
    const float* __restrict__ W1, const float* __restrict__ W2,
    const float* __restrict__ bQ, const float* __restrict__ bK,
    const float* __restrict__ bV, ushort* __restrict__ wbf, float* __restrict__ bqkv)
{
    int l = blockIdx.y;
    int idx = blockIdx.x * 256 + threadIdx.x;
    if (idx >= 786432) {
        int i = idx - 786432;   // < 768 exactly (grid sized 787200/256)
        float bv = (i < 256) ? bQ[l*256 + i]
                 : (i < 512) ? bK[l*256 + (i - 256)]
                             : bV[l*256 + (i - 512)];
        bqkv[l*768 + i] = bv;
        return;
    }
    float v;
    if (idx < 196608) {                 // WQKVt[768][256]
        int n = idx >> 8, k = idx & 255;
        v = (n < 256) ? WQ[(size_t)(l*256 + k)*256 + n]
          : (n < 512) ? WK[(size_t)(l*256 + k)*256 + (n-256)]
                      : WV[(size_t)(l*256 + k)*256 + (n-512)];
    } else if (idx < 262144) {          // WOt[256][256]
        int i = idx - 196608, n = i >> 8, k = i & 255;
        v = WO[(size_t)(l*256 + k)*256 + n];
    } else if (idx < 524288) {          // W1t[1024][256]
        int i = idx - 262144, n = i >> 8, k = i & 255;
        v = W1[(size_t)(l*256 + k)*1024 + n];
    } else {                            // W2t[256][1024]
        int i = idx - 524288, n = i >> 10, k = i & 1023;
        v = W2[(size_t)(l*1024 + k)*256 + n];
    }
    wbf[(size_t)l*786432 + idx] = f2bf(v);
}

// ---------------- outcome-token decorator (f32 out + bf16 copy) ----------------
__global__ __launch_bounds__(256) void decorate_kernel(
    const float* __restrict__ c_ctx, const float* __restrict__ c_tgt,
    const float* __restrict__ y_context, const float* __restrict__ exposure_context,
    const float* __restrict__ dec_W1, const float* __restrict__ dec_b1,
    const float* __restrict__ dec_W2, const float* __restrict__ dec_b2,
    const float* __restrict__ log_kappa, float* __restrict__ c, ushort* __restrict__ cbf)
{
    int row = blockIdx.x, tid = threadIdx.x;
    if (row >= NC_) {
        float v = c_tgt[(size_t)(row-NC_)*DD + tid];
        c[(size_t)row*DD + tid] = v;
        cbf[(size_t)row*DD + tid] = f2bf(v);
        return;
    }
    __shared__ float tv[DD];
    float y = y_context[row];
    tv[tid] = tanhf(y * dec_W1[tid] + dec_b1[tid]);
    __syncthreads();
    float kappa = log1pf(expf(log_kappa[0]));   // softplus
    float e = exposure_context[row];
    float w = e / (e + kappa);
    float acc = 0.f;
    #pragma unroll 16
    for (int k = 0; k < DD; ++k) acc += tv[k] * dec_W2[k*DD + tid];
    float v = c_ctx[(size_t)row*DD + tid] + w * (acc + dec_b2[tid]);
    c[(size_t)row*DD + tid] = v;
    cbf[(size_t)row*DD + tid] = f2bf(v);
}

// ---------------- bf16 MFMA GEMM: C[M][N] = A[M][K] @ Bt[N][K]^T + bias ----------------
// 64x64 tile, BK=64, 4 waves (2x2 of 32x32), global_load_lds w/ pre-swizzled source.
// mode: 0=f32, 1=bf16, 2=bf16 transposed, 3=bf16+relu, 4=QKV split (col<512 -> Cv
// row-major stride 512; col>=512 -> Cv2 transposed [n-512][M])
__global__ __launch_bounds__(256) void gemm_bf(
    const ushort* __restrict__ A, const ushort* __restrict__ Bt,
    const float* __restrict__ bias, void* __restrict__ Cv, void* __restrict__ Cv2,
    int M, int N, int K, int mode)
{
    __shared__ ushort As[64*64];   // [64 m][64 k], XOR-swizzled: byte ^= (row&7)<<4
    __shared__ ushort Bs[64*64];
    int tid = threadIdx.x, lane = tid & 63, w = tid >> 6;
    int wm = w >> 1, wn = w & 1;
    int m0 = blockIdx.y * 64, n0 = blockIdx.x * 64;
    int col = lane & 15, grp = lane >> 4;
    f32x4 acc[2][2] = {};

    for (int k0 = 0; k0 < K; k0 += 64) {
        __syncthreads();
        #pragma unroll
        for (int s = 0; s < 2; ++s) {
            int i = tid + s*256;
            int r = i >> 3, j = i & 7;
            int kb = (j*16) ^ ((r & 7) << 4);    // pre-swizzled source byte offset
            gload16((const char*)(A  + (size_t)(m0 + r)*K + k0) + kb,
                    (char*)As + s*4096 + w*1024);
            gload16((const char*)(Bt + (size_t)(n0 + r)*K + k0) + kb,
                    (char*)Bs + s*4096 + w*1024);
        }
        __syncthreads();
        #pragma unroll
        for (int kk = 0; kk < 64; kk += 32) {
            short8 a[2], b[2];
            #pragma unroll
            for (int f = 0; f < 2; ++f) {
                int ra = wm*32 + f*16 + col;
                a[f] = *(const short8*)((char*)As + ra*128 + (((kk + grp*8)*2) ^ ((ra & 7) << 4)));
                int rb = wn*32 + f*16 + col;
                b[f] = *(const short8*)((char*)Bs + rb*128 + (((kk + grp*8)*2) ^ ((rb & 7) << 4)));
            }
            #pragma unroll
            for (int fm = 0; fm < 2; ++fm)
                #pragma unroll
                for (int fn = 0; fn < 2; ++fn)
                    acc[fm][fn] = __builtin_amdgcn_mfma_f32_16x16x32_bf16(a[fm], b[fn], acc[fm][fn], 0, 0, 0);
        }
    }
    #pragma unroll
    for (int fm = 0; fm < 2; ++fm) {
        #pragma unroll
        for (int fn = 0; fn < 2; ++fn) {
            int ncol = n0 + wn*32 + fn*16 + col;
            int mbase = m0 + wm*32 + fm*16 + grp*4;
            float bs = bias[ncol];
            if (mode == 2 || (mode == 4 && ncol >= 512)) {
                ushort* base = (mode == 2) ? (ushort*)Cv : (ushort*)Cv2 - (size_t)512*M;
                ushort4 u;
                u.x = f2bf(acc[fm][fn][0] + bs); u.y = f2bf(acc[fm][fn][1] + bs);
                u.z = f2bf(acc[fm][fn][2] + bs); u.w = f2bf(acc[fm][fn][3] + bs);
                *(ushort4*)(base + (size_t)ncol*M + mbase) = u;
            } else if (mode == 4) {   // ncol < 512: QK row-major, stride 512
                #pragma unroll
                for (int r = 0; r < 4; ++r)
                    ((ushort*)Cv)[(size_t)(mbase + r)*512 + ncol] = f2bf(acc[fm][fn][r] + bs);
            } else {
                #pragma unroll
                for (int r = 0; r < 4; ++r) {
                    float v = acc[fm][fn][r] + bs;
                    if (mode == 3) v = fmaxf(v, 0.f);
                    if (mode == 0) ((float*)Cv)[(size_t)(mbase + r)*N + ncol] = v;
                    else           ((ushort*)Cv)[(size_t)(mbase + r)*N + ncol] = f2bf(v);
                }
            }
        }
    }
}

// ---------------- swapped-operand MFMA flash attention, in-block key-split x4 ----------------
// grid (NTOK/16, NH), 4 waves share the SAME 16 queries, each handling nk/4 keys with
// private (m,l,acc); LDS combine (exact LSE merge). Defer-max: steady tiles use in-lane
// max + __any ballot check only (no cross-lane shfl). Wave 0 applies self-key + writes out.
__global__ __launch_bounds__(256, 8) void attn_kernel(
    const ushort* __restrict__ QK, const ushort* __restrict__ Vt,
    ushort* __restrict__ AO)
{
    __shared__ ushort P_lds[4][16*64];     // 8 KB, wave-private P, XOR-swizzled
    __shared__ float cacc[4][32][17];      // 8.7 KB combine buffer (padded stride 17)
    __shared__ float cml[4][2][16];        // m, l per wave per query
    int tid = threadIdx.x;
    int w = tid >> 6, lane = tid & 63;
    int q = lane & 15, g = lane >> 4;
    int h = blockIdx.y;
    int q0 = blockIdx.x * 16;
    char* pb = (char*)P_lds[w];
    const float C = 0.25503483f;    // log2(e)/sqrt(32)
    const int swz = (q & 7) << 4;

    short8 bq = *(const short8*)&QK[(size_t)(q0 + q)*512 + h*HDIM + g*8];

    f32x4 acc0 = {0.f,0.f,0.f,0.f}, acc1 = {0.f,0.f,0.f,0.f};
    float mC = -INFINITY, lsum = 0.f;

    const int is_tgt = (q0 >= NC_);
    const int nk = is_tgt ? NC_ : NTOK;
    const int nkw = nk >> 2;
    const int kstart = w * nkw, kend = kstart + nkw;
    const ushort* kbase = QK + (size_t)q*512 + 256 + h*HDIM + g*8;
    const ushort* vb0 = Vt + (size_t)(h*HDIM + q)*NTOK + g*8;
    const ushort* vb1 = vb0 + (size_t)16*NTOK;
    const f32x4 z = {0.f,0.f,0.f,0.f};

    for (int kb = kstart; kb < kend; kb += 64) {
        f32x4 st[4];
        #pragma unroll
        for (int t = 0; t < 4; ++t) {
            short8 ka = *(const short8*)(kbase + (size_t)(kb + 16*t)*512);
            st[t] = __builtin_amdgcn_mfma_f32_16x16x32_bf16(ka, bq, z, 0, 0, 0);
        }
        // in-lane max over this lane's 16 scores
        float x0 = fmaxf(fmaxf(st[0][0], st[0][1]), fmaxf(st[0][2], st[0][3]));
        float x1 = fmaxf(fmaxf(st[1][0], st[1][1]), fmaxf(st[1][2], st[1][3]));
        float x2 = fmaxf(fmaxf(st[2][0], st[2][1]), fmaxf(st[2][2], st[2][3]));
        float x3 = fmaxf(fmaxf(st[3][0], st[3][1]), fmaxf(st[3][2], st[3][3]));
        float mxC = fmaxf(fmaxf(x0, x1), fmaxf(x2, x3)) * C;
        // defer-max: rescale only if some lane's max exceeds running max + 8
        if (__any(mxC > mC + 8.f)) {
            float M = mxC;
            M = fmaxf(M, __shfl_xor(M, 16, 64));
            M = fmaxf(M, __shfl_xor(M, 32, 64));
            float mCn = fmaxf(mC, M);
            float corr = EXP2(mC - mCn);
            acc0 *= corr; acc1 *= corr; lsum *= corr;
            mC = mCn;
        }
        float p[16];
        #pragma unroll
        for (int t = 0; t < 4; ++t)
            #pragma unroll
            for (int r = 0; r < 4; ++r)
                p[t*4 + r] = EXP2(st[t][r]*C - mC);
        float s01 = (p[0]+p[1]) + (p[2]+p[3]),  s23 = (p[4]+p[5]) + (p[6]+p[7]);
        float s45 = (p[8]+p[9]) + (p[10]+p[11]), s67 = (p[12]+p[13]) + (p[14]+p[15]);
        lsum += (s01 + s23) + (s45 + s67);
        #pragma unroll
        for (int t = 0; t < 4; ++t) {
            uint2 dd;
            dd.x = (uint)f2bf(p[t*4+0]) | ((uint)f2bf(p[t*4+1]) << 16);
            dd.y = (uint)f2bf(p[t*4+2]) | ((uint)f2bf(p[t*4+3]) << 16);
            *(uint2*)(pb + q*128 + (((16*t + 4*g)*2) ^ swz)) = dd;
        }
        #pragma unroll
        for (int c = 0; c < 2; ++c) {
            short8 pfrag = *(const short8*)(pb + q*128 + (((32*c + 8*g)*2) ^ swz));
            short8 va0 = *(const short8*)(vb0 + kb + 32*c);
            short8 va1 = *(const short8*)(vb1 + kb + 32*c);
            acc0 = __builtin_amdgcn_mfma_f32_16x16x32_bf16(va0, pfrag, acc0, 0, 0, 0);
            acc1 = __builtin_amdgcn_mfma_f32_16x16x32_bf16(va1, pfrag, acc1, 0, 0, 0);
        }
    }

    if (is_tgt && w == 0) {   // self-key (structural mask), applied once in wave 0
        int qg = q0 + q;
        short8 kv = *(const short8*)&QK[(size_t)qg*512 + 256 + h*HDIM + g*8];
        float d8 = 0.f;
        #pragma unroll
        for (int e = 0; e < 8; ++e) d8 += bf2f((ushort)bq[e]) * bf2f((ushort)kv[e]);
        d8 += __shfl_xor(d8, 16, 64);
        d8 += __shfl_xor(d8, 32, 64);
        float sC = d8 * C;
        float mCn = fmaxf(mC, sC);
        float corr = EXP2(mC - mCn);
        float pp = EXP2(sC - mCn);
        mC = mCn;
        lsum = lsum*corr + ((g == 0) ? pp : 0.f);
        acc0 *= corr; acc1 *= corr;
        #pragma unroll
        for (int r = 0; r < 4; ++r) {
            acc0[r] += pp * bf2f(Vt[(size_t)(h*HDIM + g*4 + r)*NTOK + qg]);
            acc1[r] += pp * bf2f(Vt[(size_t)(h*HDIM + 16 + g*4 + r)*NTOK + qg]);
        }
    }

    // reduce l across the 4 groups (one-time), publish partials
    lsum += __shfl_xor(lsum, 16, 64);
    lsum += __shfl_xor(lsum, 32, 64);
    #pragma unroll
    for (int r = 0; r < 4; ++r) {
        cacc[w][g*4 + r][q]      = acc0[r];
        cacc[w][16 + g*4 + r][q] = acc1[r];
    }
    if (g == 0) { cml[w][0][q] = mC; cml[w][1][q] = lsum; }
    __syncthreads();

    if (w == 0) {   // exact LSE combine across the 4 key-chunks
        float m0_ = cml[0][0][q], m1_ = cml[1][0][q], m2_ = cml[2][0][q], m3_ = cml[3][0][q];
        float l0 = cml[0][1][q], l1 = cml[1][1][q], l2 = cml[2][1][q], l3 = cml[3][1][q];
        float M = fmaxf(fmaxf(m0_, m1_), fmaxf(m2_, m3_));
        float f0 = EXP2(m0_ - M), f1 = EXP2(m1_ - M), f2 = EXP2(m2_ - M), f3 = EXP2(m3_ - M);
        float inv = 1.f / (l0*f0 + l1*f1 + l2*f2 + l3*f3);
        ushort* dst = AO + (size_t)(q0 + q)*DD + h*HDIM;
        ushort4 o0, o1;
        #pragma unroll
        for (int r = 0; r < 4; ++r) {
            int d0 = g*4 + r, d1 = 16 + g*4 + r;
            float O0 = cacc[0][d0][q]*f0 + cacc[1][d0][q]*f1 + cacc[2][d0][q]*f2 + cacc[3][d0][q]*f3;
            float O1 = cacc[0][d1][q]*f0 + cacc[1][d1][q]*f1 + cacc[2][d1][q]*f2 + cacc[3][d1][q]*f3;
            ((ushort*)&o0)[r] = f2bf(O0 * inv);
            ((ushort*)&o1)[r] = f2bf(O1 * inv);
        }
        *(ushort4*)(dst + g*4) = o0;
        *(ushort4*)(dst + 16 + g*4) = o1;
    }
}

// ---------------- layernorm: c = LN(c + delta)*g + b ; + bf16 copy ----------------
__global__ __launch_bounds__(256) void ln_kernel(
    float* __restrict__ c, const float* __restrict__ delta,
    const float* __restrict__ g, const float* __restrict__ b, ushort* __restrict__ cbf)
{
    int tid = threadIdx.x;
    int wid = tid >> 6, lane = tid & 63;
    int row = blockIdx.x * 4 + wid;
    float4 x  = *(const float4*)&c[(size_t)row*DD + lane*4];
    float4 dl = *(const float4*)&delta[(size_t)row*DD + lane*4];
    x.x += dl.x; x.y += dl.y; x.z += dl.z; x.w += dl.w;
    float s = x.x + x.y + x.z + x.w;
    #pragma unroll
    for (int off = 1; off < 64; off <<= 1) s += __shfl_xor(s, off, 64);
    float mean = s * (1.f/DD);
    float dx = x.x-mean, dy = x.y-mean, dz = x.z-mean, dw = x.w-mean;
    float v = dx*dx + dy*dy + dz*dz + dw*dw;
    #pragma unroll
    for (int off = 1; off < 64; off <<= 1) v += __shfl_xor(v, off, 64);
    float rstd = rsqrtf(v*(1.f/DD) + 1e-5f);
    float4 g4 = *(const float4*)&g[lane*4];
    float4 b4 = *(const float4*)&b[lane*4];
    float4 o;
    o.x = dx*rstd*g4.x + b4.x;
    o.y = dy*rstd*g4.y + b4.y;
    o.z = dz*rstd*g4.z + b4.z;
    o.w = dw*rstd*g4.w + b4.w;
    *(float4*)&c[(size_t)row*DD + lane*4] = o;
    ushort4 u;
    u.x = f2bf(o.x); u.y = f2bf(o.y); u.z = f2bf(o.z); u.w = f2bf(o.w);
    *(ushort4*)&cbf[(size_t)row*DD + lane*4] = u;
}

// ---------------- head: out = exp(c_tgt @ out_W + out_b) * exposure ----------------
__global__ __launch_bounds__(256) void out_kernel(
    const float* __restrict__ c, const float* __restrict__ out_W,
    const float* __restrict__ out_b, const float* __restrict__ exposure_target,
    float* __restrict__ out)
{
    int tid = threadIdx.x;
    int wid = tid >> 6, lane = tid & 63;
    int r = blockIdx.x * 4 + wid;
    float4 cv = *(const float4*)&c[(size_t)(NC_ + r)*DD + lane*4];
    float4 wv = *(const float4*)&out_W[lane*4];
    float s = cv.x*wv.x + cv.y*wv.y + cv.z*wv.z + cv.w*wv.w;
    #pragma unroll
    for (int off = 1; off < 64; off <<= 1) s += __shfl_xor(s, off, 64);
    if (lane == 0) out[r] = expf(s + out_b[0]) * exposure_target[r];
}

extern "C" void kernel_launch(void* const* d_in, const int* in_sizes, int n_in,
                              void* d_out, int out_size, void* d_ws, size_t ws_size,
                              hipStream_t stream) {
    const float* c_ctx            = (const float*)d_in[0];
    const float* c_tgt            = (const float*)d_in[1];
    const float* y_context        = (const float*)d_in[2];
    const float* exposure_context = (const float*)d_in[3];
    const float* exposure_target  = (const float*)d_in[4];
    const float* dec_W1           = (const float*)d_in[5];
    const float* dec_b1           = (const float*)d_in[6];
    const float* dec_W2           = (const float*)d_in[7];
    const float* dec_b2           = (const float*)d_in[8];
    const float* log_kappa        = (const float*)d_in[9];
    const float* WQ               = (const float*)d_in[10];
    const float* bQ               = (const float*)d_in[11];
    const float* WK               = (const float*)d_in[12];
    const float* bK               = (const float*)d_in[13];
    const float* WV               = (const float*)d_in[14];
    const float* bV               = (const float*)d_in[15];
    const float* WO               = (const float*)d_in[16];
    const float* bO               = (const float*)d_in[17];
    const float* ln1_g            = (const float*)d_in[18];
    const float* ln1_b            = (const float*)d_in[19];
    const float* ln2_g            = (const float*)d_in[20];
    const float* ln2_b            = (const float*)d_in[21];
    const float* ffn_W1           = (const float*)d_in[22];
    const float* ffn_b1           = (const float*)d_in[23];
    const float* ffn_W2           = (const float*)d_in[24];
    const float* ffn_b2           = (const float*)d_in[25];
    const float* out_W            = (const float*)d_in[26];
    const float* out_b            = (const float*)d_in[27];
    float* out = (float*)d_out;

    float* ws = (float*)d_ws;
    float*  c    = ws;                          // 4096*256 f32
    float*  T    = ws + 1048576;                // 4096*256 f32
    ushort* ub   = (ushort*)(ws + 2097152);
    ushort* c_bf = ub;                          // 4096*256 bf16
    ushort* QKb  = ub + 1048576;                // 4096*512 bf16
    ushort* Vt   = ub + 3145728;                // 256*4096 bf16 (V transposed)
    ushort* AO   = ub + 4194304;                // 4096*256 bf16
    ushort* wbf  = ub + 5242880;                // 2*786432 bf16 weights
    float*  bqkv = (float*)(ub + 6815744);      // 2*768 f32
    ushort* Hd   = QKb;                         // 4096*1024 bf16, aliases QKb+Vt+AO

    convert_kernel<<<dim3(3075, 2), 256, 0, stream>>>(WQ, WK, WV, WO, ffn_W1, ffn_W2,
                                                      bQ, bK, bV, wbf, bqkv);
    decorate_kernel<<<NTOK, 256, 0, stream>>>(c_ctx, c_tgt, y_context, exposure_context,
                                              dec_W1, dec_b1, dec_W2, dec_b2, log_kappa, c, c_bf);
    for (int l = 0; l < NL; ++l) {
        ushort* wl = wbf + (size_t)l*786432;
        gemm_bf<<<dim3(12, 64), 256, 0, stream>>>(c_bf, wl, bqkv + l*768, QKb, Vt, NTOK, 768, DD, 4);
        attn_kernel<<<dim3(NTOK/16, NH), 256, 0, stream>>>(QKb, Vt, AO);
        gemm_bf<<<dim3(4, 64),  256, 0, stream>>>(AO,   wl + 196608, bO + l*DD,      T,  nullptr, NTOK, DD, DD, 0);
        ln_kernel<<<NTOK/4, 256, 0, stream>>>(c, T, ln1_g + l*DD, ln1_b + l*DD, c_bf);
        gemm_bf<<<dim3(16, 64), 256, 0, stream>>>(c_bf, wl + 262144, ffn_b1 + l*FFD, Hd, nullptr, NTOK, FFD, DD, 3);
        gemm_bf<<<dim3(4, 64),  256, 0, stream>>>(Hd,   wl + 524288, ffn_b2 + l*DD,  T,  nullptr, NTOK, DD, FFD, 0);
        ln_kernel<<<NTOK/4, 256, 0, stream>>>(c, T, ln2_g + l*DD, ln2_b + l*DD, c_bf);
    }
    out_kernel<<<NT_/4, 256, 0, stream>>>(c, out_W, out_b, exposure_target, out);
}

// Round 5
// 245.559 us; speedup vs baseline: 18.4160x; 1.4613x over previous
//
#include <hip/hip_runtime.h>
#include <hip/hip_bf16.h>
#include <math.h>

#define NC_   3072
#define NT_   1024
#define NTOK  4096
#define DD    256
#define NH    8
#define HDIM  32
#define NL    2
#define FFD   1024

typedef __attribute__((ext_vector_type(8))) short short8;
typedef __attribute__((ext_vector_type(4))) float f32x4;

#if __has_builtin(__builtin_amdgcn_exp2f)
#define EXP2(x) __builtin_amdgcn_exp2f(x)
#else
#define EXP2(x) exp2f(x)
#endif

__device__ inline float bf2f(ushort u) { return __uint_as_float(((unsigned)u) << 16); }
__device__ inline ushort f2bf(float x) {
    __hip_bfloat16 h = __float2bfloat16(x);
    return *reinterpret_cast<ushort*>(&h);
}
__device__ inline void gload16(const void* g, void* l) {
    __builtin_amdgcn_global_load_lds(
        (const __attribute__((address_space(1))) void*)g,
        (__attribute__((address_space(3))) void*)l, 16, 0, 0);
}

// ---------------- weight convert: fp32 [K][N] -> bf16 transposed [N][K], + bQKV concat ----
// packed per-layer (elements): WQKVt[768][256] 0..196607 | WOt 196608 | W1t 262144 | W2t 524288
__global__ __launch_bounds__(256) void convert_kernel(
    const float* __restrict__ WQ, const float* __restrict__ WK,
    const float* __restrict__ WV, const float* __restrict__ WO,
    const float* __restrict__ W1, const float* __restrict__ W2,
    const float* __restrict__ bQ, const float* __restrict__ bK,
    const float* __restrict__ bV, ushort* __restrict__ wbf, float* __restrict__ bqkv)
{
    int l = blockIdx.y;
    int idx = blockIdx.x * 256 + threadIdx.x;
    if (idx >= 786432) {
        int i = idx - 786432;   // < 768 exactly (grid sized 787200/256)
        float bv = (i < 256) ? bQ[l*256 + i]
                 : (i < 512) ? bK[l*256 + (i - 256)]
                             : bV[l*256 + (i - 512)];
        bqkv[l*768 + i] = bv;
        return;
    }
    float v;
    if (idx < 196608) {                 // WQKVt[768][256]
        int n = idx >> 8, k = idx & 255;
        v = (n < 256) ? WQ[(size_t)(l*256 + k)*256 + n]
          : (n < 512) ? WK[(size_t)(l*256 + k)*256 + (n-256)]
                      : WV[(size_t)(l*256 + k)*256 + (n-512)];
    } else if (idx < 262144) {          // WOt[256][256]
        int i = idx - 196608, n = i >> 8, k = i & 255;
        v = WO[(size_t)(l*256 + k)*256 + n];
    } else if (idx < 524288) {          // W1t[1024][256]
        int i = idx - 262144, n = i >> 8, k = i & 255;
        v = W1[(size_t)(l*256 + k)*1024 + n];
    } else {                            // W2t[256][1024]
        int i = idx - 524288, n = i >> 10, k = i & 1023;
        v = W2[(size_t)(l*1024 + k)*256 + n];
    }
    wbf[(size_t)l*786432 + idx] = f2bf(v);
}

// ---------------- outcome-token decorator (f32 out + bf16 copy) ----------------
__global__ __launch_bounds__(256) void decorate_kernel(
    const float* __restrict__ c_ctx, const float* __restrict__ c_tgt,
    const float* __restrict__ y_context, const float* __restrict__ exposure_context,
    const float* __restrict__ dec_W1, const float* __restrict__ dec_b1,
    const float* __restrict__ dec_W2, const float* __restrict__ dec_b2,
    const float* __restrict__ log_kappa, float* __restrict__ c, ushort* __restrict__ cbf)
{
    int row = blockIdx.x, tid = threadIdx.x;
    if (row >= NC_) {
        float v = c_tgt[(size_t)(row-NC_)*DD + tid];
        c[(size_t)row*DD + tid] = v;
        cbf[(size_t)row*DD + tid] = f2bf(v);
        return;
    }
    __shared__ float tv[DD];
    float y = y_context[row];
    tv[tid] = tanhf(y * dec_W1[tid] + dec_b1[tid]);
    __syncthreads();
    float kappa = log1pf(expf(log_kappa[0]));   // softplus
    float e = exposure_context[row];
    float w = e / (e + kappa);
    float acc = 0.f;
    #pragma unroll 16
    for (int k = 0; k < DD; ++k) acc += tv[k] * dec_W2[k*DD + tid];
    float v = c_ctx[(size_t)row*DD + tid] + w * (acc + dec_b2[tid]);
    c[(size_t)row*DD + tid] = v;
    cbf[(size_t)row*DD + tid] = f2bf(v);
}

// ---------------- bf16 MFMA GEMM: C[M][N] = A[M][K] @ Bt[N][K]^T + bias ----------------
// 64x64 tile, BK=64, 4 waves (2x2 of 32x32), global_load_lds w/ pre-swizzled source.
// mode: 0=f32, 1=bf16, 2=bf16 transposed, 3=bf16+relu, 4=QKV split (col<512 -> Cv
// row-major stride 512; col>=512 -> Cv2 transposed [n-512][M])
__global__ __launch_bounds__(256) void gemm_bf(
    const ushort* __restrict__ A, const ushort* __restrict__ Bt,
    const float* __restrict__ bias, void* __restrict__ Cv, void* __restrict__ Cv2,
    int M, int N, int K, int mode)
{
    __shared__ ushort As[64*64];   // [64 m][64 k], XOR-swizzled: byte ^= (row&7)<<4
    __shared__ ushort Bs[64*64];
    int tid = threadIdx.x, lane = tid & 63, w = tid >> 6;
    int wm = w >> 1, wn = w & 1;
    int m0 = blockIdx.y * 64, n0 = blockIdx.x * 64;
    int col = lane & 15, grp = lane >> 4;
    f32x4 acc[2][2] = {};

    for (int k0 = 0; k0 < K; k0 += 64) {
        __syncthreads();
        #pragma unroll
        for (int s = 0; s < 2; ++s) {
            int i = tid + s*256;
            int r = i >> 3, j = i & 7;
            int kb = (j*16) ^ ((r & 7) << 4);    // pre-swizzled source byte offset
            gload16((const char*)(A  + (size_t)(m0 + r)*K + k0) + kb,
                    (char*)As + s*4096 + w*1024);
            gload16((const char*)(Bt + (size_t)(n0 + r)*K + k0) + kb,
                    (char*)Bs + s*4096 + w*1024);
        }
        __syncthreads();
        #pragma unroll
        for (int kk = 0; kk < 64; kk += 32) {
            short8 a[2], b[2];
            #pragma unroll
            for (int f = 0; f < 2; ++f) {
                int ra = wm*32 + f*16 + col;
                a[f] = *(const short8*)((char*)As + ra*128 + (((kk + grp*8)*2) ^ ((ra & 7) << 4)));
                int rb = wn*32 + f*16 + col;
                b[f] = *(const short8*)((char*)Bs + rb*128 + (((kk + grp*8)*2) ^ ((rb & 7) << 4)));
            }
            #pragma unroll
            for (int fm = 0; fm < 2; ++fm)
                #pragma unroll
                for (int fn = 0; fn < 2; ++fn)
                    acc[fm][fn] = __builtin_amdgcn_mfma_f32_16x16x32_bf16(a[fm], b[fn], acc[fm][fn], 0, 0, 0);
        }
    }
    #pragma unroll
    for (int fm = 0; fm < 2; ++fm) {
        #pragma unroll
        for (int fn = 0; fn < 2; ++fn) {
            int ncol = n0 + wn*32 + fn*16 + col;
            int mbase = m0 + wm*32 + fm*16 + grp*4;
            float bs = bias[ncol];
            if (mode == 2 || (mode == 4 && ncol >= 512)) {
                ushort* base = (mode == 2) ? (ushort*)Cv : (ushort*)Cv2 - (size_t)512*M;
                ushort4 u;
                u.x = f2bf(acc[fm][fn][0] + bs); u.y = f2bf(acc[fm][fn][1] + bs);
                u.z = f2bf(acc[fm][fn][2] + bs); u.w = f2bf(acc[fm][fn][3] + bs);
                *(ushort4*)(base + (size_t)ncol*M + mbase) = u;
            } else if (mode == 4) {   // ncol < 512: QK row-major, stride 512
                #pragma unroll
                for (int r = 0; r < 4; ++r)
                    ((ushort*)Cv)[(size_t)(mbase + r)*512 + ncol] = f2bf(acc[fm][fn][r] + bs);
            } else {
                #pragma unroll
                for (int r = 0; r < 4; ++r) {
                    float v = acc[fm][fn][r] + bs;
                    if (mode == 3) v = fmaxf(v, 0.f);
                    if (mode == 0) ((float*)Cv)[(size_t)(mbase + r)*N + ncol] = v;
                    else           ((ushort*)Cv)[(size_t)(mbase + r)*N + ncol] = f2bf(v);
                }
            }
        }
    }
}

// ---------------- LDS-staged flash attention, 8 waves, 64 queries/block ----------------
// grid (NTOK/64, NH), block 512. Waves 0-3: query-group w, key-half 0; waves 4-7:
// query-group w-4, key-half 1. K/V tiles (64 keys) staged ONCE per block, double-
// buffered: V via global_load_lds (source-preswizzled), K reg-staged into 72B-padded
// rows. Raw s_barrier + per-role counted waits keep prefetch in flight. LSE-merge
// combine across the two key-halves. Targets: keys [0,NC) + explicit self-key.
__global__ __launch_bounds__(512, 4) void attn_kernel(
    const ushort* __restrict__ QK, const ushort* __restrict__ Vt,
    ushort* __restrict__ AO)
{
    __shared__ ushort Ks[2][64*36];      // 72B rows (64B data + 8B pad) -> ~2-way reads
    __shared__ ushort Vs[2][32*64];      // [32 d][64 k], slot^(row&7) swizzle
    __shared__ ushort P_lds[8][16*32];   // per-wave P tile, (q&3) slot-XOR
    __shared__ float cacc[8][32][17];
    __shared__ float cml[8][2][16];

    int tid = threadIdx.x;
    int w = tid >> 6, lane = tid & 63;
    int q_lo = lane & 15, g = lane >> 4;
    int wq = w & 3, kh = w >> 2;
    int h = blockIdx.y;
    int q0 = blockIdx.x * 64;
    char* pb = (char*)P_lds[w];
    const float C = 0.25503483f;    // log2(e)/sqrt(32)

    // Q B-frag (global, once)
    short8 bq = *(const short8*)&QK[(size_t)(q0 + wq*16 + q_lo)*512 + h*HDIM + g*8];

    f32x4 acc0 = {0.f,0.f,0.f,0.f}, acc1 = {0.f,0.f,0.f,0.f};
    float mC = -INFINITY, lsum = 0.f;
    const f32x4 z = {0.f,0.f,0.f,0.f};

    const int is_tgt = (q0 >= NC_);
    const int nk = is_tgt ? NC_ : NTOK;
    const int nt = nk >> 6;

    // staging roles
    int vrow = tid >> 3, vslot = tid & 7;                    // V: threads 0-255
    const ushort* vsrc0 = Vt + (size_t)(h*HDIM + vrow)*NTOK + ((vslot ^ (vrow & 7)) << 3);
    int kkey = (tid - 256) >> 2, kslot = tid & 3;            // K: threads 256-511
    const ushort* ksrc0 = QK + (size_t)kkey*512 + 256 + h*HDIM + kslot*8;
    short8 kreg;

    // ---- prologue: stage tile 0, preload K tile 1 ----
    if (w < 4) {
        gload16(vsrc0, (char*)Vs[0] + w*1024);
        asm volatile("s_waitcnt vmcnt(0)" ::: "memory");
    } else {
        kreg = *(const short8*)(ksrc0);
        asm volatile("s_waitcnt vmcnt(0)" ::: "memory");
        *(short8*)((char*)Ks[0] + kkey*72 + kslot*16) = kreg;
        if (nt > 1) kreg = *(const short8*)(ksrc0 + (size_t)64*512);
        asm volatile("s_waitcnt lgkmcnt(0)" ::: "memory");
    }
    __builtin_amdgcn_s_barrier();
    __builtin_amdgcn_sched_barrier(0);

    for (int t = 0; t < nt; ++t) {
        int cur = t & 1, nxt = cur ^ 1;
        if (t + 1 < nt) {   // issue staging for tile t+1
            if (w < 4) {
                gload16(vsrc0 + (size_t)(t+1)*64, (char*)Vs[nxt] + w*1024);
            } else {
                asm volatile("s_waitcnt vmcnt(0)" ::: "memory");   // K(t+1) reg ready
                *(short8*)((char*)Ks[nxt] + kkey*72 + kslot*16) = kreg;
                if (t + 2 < nt) kreg = *(const short8*)(ksrc0 + (size_t)(t+2)*64*512);
            }
        }
        // ---- compute tile t: this wave's 32 keys (half kh) ----
        short8 ka0 = *(const short8*)((char*)Ks[cur] + (kh*32 +      q_lo)*72 + g*16);
        short8 ka1 = *(const short8*)((char*)Ks[cur] + (kh*32 + 16 + q_lo)*72 + g*16);
        f32x4 st0 = __builtin_amdgcn_mfma_f32_16x16x32_bf16(ka0, bq, z, 0, 0, 0);
        f32x4 st1 = __builtin_amdgcn_mfma_f32_16x16x32_bf16(ka1, bq, z, 0, 0, 0);
        float mx = fmaxf(fmaxf(fmaxf(st0[0], st0[1]), fmaxf(st0[2], st0[3])),
                         fmaxf(fmaxf(st1[0], st1[1]), fmaxf(st1[2], st1[3]))) * C;
        if (__any(mx > mC + 8.f)) {     // deferred wave-uniform rescale
            float M = mx;
            M = fmaxf(M, __shfl_xor(M, 16, 64));
            M = fmaxf(M, __shfl_xor(M, 32, 64));
            float mCn = fmaxf(mC, M);
            float corr = EXP2(mC - mCn);
            acc0 *= corr; acc1 *= corr; lsum *= corr;
            mC = mCn;
        }
        float p[8];
        #pragma unroll
        for (int r = 0; r < 4; ++r) { p[r] = EXP2(st0[r]*C - mC); p[4+r] = EXP2(st1[r]*C - mC); }
        lsum += ((p[0]+p[1]) + (p[2]+p[3])) + ((p[4]+p[5]) + (p[6]+p[7]));
        const int swz = (q_lo & 3) << 4;
        uint2 d0, d1;
        d0.x = (uint)f2bf(p[0]) | ((uint)f2bf(p[1]) << 16);
        d0.y = (uint)f2bf(p[2]) | ((uint)f2bf(p[3]) << 16);
        d1.x = (uint)f2bf(p[4]) | ((uint)f2bf(p[5]) << 16);
        d1.y = (uint)f2bf(p[6]) | ((uint)f2bf(p[7]) << 16);
        *(uint2*)(pb + q_lo*64 + (((     4*g)*2) ^ swz)) = d0;
        *(uint2*)(pb + q_lo*64 + (((16 + 4*g)*2) ^ swz)) = d1;
        short8 pfrag = *(const short8*)(pb + q_lo*64 + ((16*g) ^ swz));
        short8 va0 = *(const short8*)((char*)Vs[cur] + q_lo*128      + (((4*kh + g) ^ (q_lo & 7)) << 4));
        short8 va1 = *(const short8*)((char*)Vs[cur] + (16+q_lo)*128 + (((4*kh + g) ^ (q_lo & 7)) << 4));
        acc0 = __builtin_amdgcn_mfma_f32_16x16x32_bf16(va0, pfrag, acc0, 0, 0, 0);
        acc1 = __builtin_amdgcn_mfma_f32_16x16x32_bf16(va1, pfrag, acc1, 0, 0, 0);
        // ---- staging drain + barrier ----
        if (t + 1 < nt) {
            if (w < 4) asm volatile("s_waitcnt vmcnt(0)" ::: "memory");
            else       asm volatile("s_waitcnt lgkmcnt(0)" ::: "memory");
            __builtin_amdgcn_s_barrier();
            __builtin_amdgcn_sched_barrier(0);
        }
    }

    if (is_tgt && kh == 0) {   // self-key, once (wave-half 0)
        int qg = q0 + wq*16 + q_lo;
        short8 kv = *(const short8*)&QK[(size_t)qg*512 + 256 + h*HDIM + g*8];
        float d8 = 0.f;
        #pragma unroll
        for (int e = 0; e < 8; ++e) d8 += bf2f((ushort)bq[e]) * bf2f((ushort)kv[e]);
        d8 += __shfl_xor(d8, 16, 64);
        d8 += __shfl_xor(d8, 32, 64);
        float sC = d8 * C;
        float mCn = fmaxf(mC, sC);
        float corr = EXP2(mC - mCn);
        float pp = EXP2(sC - mCn);
        mC = mCn;
        lsum = lsum*corr + ((g == 0) ? pp : 0.f);
        acc0 *= corr; acc1 *= corr;
        #pragma unroll
        for (int r = 0; r < 4; ++r) {
            acc0[r] += pp * bf2f(Vt[(size_t)(h*HDIM + g*4 + r)*NTOK + qg]);
            acc1[r] += pp * bf2f(Vt[(size_t)(h*HDIM + 16 + g*4 + r)*NTOK + qg]);
        }
    }

    // publish partials
    lsum += __shfl_xor(lsum, 16, 64);
    lsum += __shfl_xor(lsum, 32, 64);
    #pragma unroll
    for (int r = 0; r < 4; ++r) {
        cacc[w][g*4 + r][q_lo]      = acc0[r];
        cacc[w][16 + g*4 + r][q_lo] = acc1[r];
    }
    if (g == 0) { cml[w][0][q_lo] = mC; cml[w][1][q_lo] = lsum; }
    __syncthreads();

    if (w < 4) {   // LSE merge of halves (w, w+4)
        float m0_ = cml[w][0][q_lo], m1_ = cml[w+4][0][q_lo];
        float l0 = cml[w][1][q_lo], l1 = cml[w+4][1][q_lo];
        float M = fmaxf(m0_, m1_);
        float f0 = EXP2(m0_ - M), f1 = EXP2(m1_ - M);
        float inv = 1.f / (l0*f0 + l1*f1);
        ushort* dst = AO + (size_t)(q0 + wq*16 + q_lo)*DD + h*HDIM;
        ushort4 o0, o1;
        #pragma unroll
        for (int r = 0; r < 4; ++r) {
            int e0 = g*4 + r, e1 = 16 + g*4 + r;
            float O0 = cacc[w][e0][q_lo]*f0 + cacc[w+4][e0][q_lo]*f1;
            float O1 = cacc[w][e1][q_lo]*f0 + cacc[w+4][e1][q_lo]*f1;
            ((ushort*)&o0)[r] = f2bf(O0 * inv);
            ((ushort*)&o1)[r] = f2bf(O1 * inv);
        }
        *(ushort4*)(dst + g*4) = o0;
        *(ushort4*)(dst + 16 + g*4) = o1;
    }
}

// ---------------- layernorm: c = LN(c + delta)*g + b ; + bf16 copy ----------------
__global__ __launch_bounds__(256) void ln_kernel(
    float* __restrict__ c, const float* __restrict__ delta,
    const float* __restrict__ g, const float* __restrict__ b, ushort* __restrict__ cbf)
{
    int tid = threadIdx.x;
    int wid = tid >> 6, lane = tid & 63;
    int row = blockIdx.x * 4 + wid;
    float4 x  = *(const float4*)&c[(size_t)row*DD + lane*4];
    float4 dl = *(const float4*)&delta[(size_t)row*DD + lane*4];
    x.x += dl.x; x.y += dl.y; x.z += dl.z; x.w += dl.w;
    float s = x.x + x.y + x.z + x.w;
    #pragma unroll
    for (int off = 1; off < 64; off <<= 1) s += __shfl_xor(s, off, 64);
    float mean = s * (1.f/DD);
    float dx = x.x-mean, dy = x.y-mean, dz = x.z-mean, dw = x.w-mean;
    float v = dx*dx + dy*dy + dz*dz + dw*dw;
    #pragma unroll
    for (int off = 1; off < 64; off <<= 1) v += __shfl_xor(v, off, 64);
    float rstd = rsqrtf(v*(1.f/DD) + 1e-5f);
    float4 g4 = *(const float4*)&g[lane*4];
    float4 b4 = *(const float4*)&b[lane*4];
    float4 o;
    o.x = dx*rstd*g4.x + b4.x;
    o.y = dy*rstd*g4.y + b4.y;
    o.z = dz*rstd*g4.z + b4.z;
    o.w = dw*rstd*g4.w + b4.w;
    *(float4*)&c[(size_t)row*DD + lane*4] = o;
    ushort4 u;
    u.x = f2bf(o.x); u.y = f2bf(o.y); u.z = f2bf(o.z); u.w = f2bf(o.w);
    *(ushort4*)&cbf[(size_t)row*DD + lane*4] = u;
}

// ---------------- head: out = exp(c_tgt @ out_W + out_b) * exposure ----------------
__global__ __launch_bounds__(256) void out_kernel(
    const float* __restrict__ c, const float* __restrict__ out_W,
    const float* __restrict__ out_b, const float* __restrict__ exposure_target,
    float* __restrict__ out)
{
    int tid = threadIdx.x;
    int wid = tid >> 6, lane = tid & 63;
    int r = blockIdx.x * 4 + wid;
    float4 cv = *(const float4*)&c[(size_t)(NC_ + r)*DD + lane*4];
    float4 wv = *(const float4*)&out_W[lane*4];
    float s = cv.x*wv.x + cv.y*wv.y + cv.z*wv.z + cv.w*wv.w;
    #pragma unroll
    for (int off = 1; off < 64; off <<= 1) s += __shfl_xor(s, off, 64);
    if (lane == 0) out[r] = expf(s + out_b[0]) * exposure_target[r];
}

extern "C" void kernel_launch(void* const* d_in, const int* in_sizes, int n_in,
                              void* d_out, int out_size, void* d_ws, size_t ws_size,
                              hipStream_t stream) {
    const float* c_ctx            = (const float*)d_in[0];
    const float* c_tgt            = (const float*)d_in[1];
    const float* y_context        = (const float*)d_in[2];
    const float* exposure_context = (const float*)d_in[3];
    const float* exposure_target  = (const float*)d_in[4];
    const float* dec_W1           = (const float*)d_in[5];
    const float* dec_b1           = (const float*)d_in[6];
    const float* dec_W2           = (const float*)d_in[7];
    const float* dec_b2           = (const float*)d_in[8];
    const float* log_kappa        = (const float*)d_in[9];
    const float* WQ               = (const float*)d_in[10];
    const float* bQ               = (const float*)d_in[11];
    const float* WK               = (const float*)d_in[12];
    const float* bK               = (const float*)d_in[13];
    const float* WV               = (const float*)d_in[14];
    const float* bV               = (const float*)d_in[15];
    const float* WO               = (const float*)d_in[16];
    const float* bO               = (const float*)d_in[17];
    const float* ln1_g            = (const float*)d_in[18];
    const float* ln1_b            = (const float*)d_in[19];
    const float* ln2_g            = (const float*)d_in[20];
    const float* ln2_b            = (const float*)d_in[21];
    const float* ffn_W1           = (const float*)d_in[22];
    const float* ffn_b1           = (const float*)d_in[23];
    const float* ffn_W2           = (const float*)d_in[24];
    const float* ffn_b2           = (const float*)d_in[25];
    const float* out_W            = (const float*)d_in[26];
    const float* out_b            = (const float*)d_in[27];
    float* out = (float*)d_out;

    float* ws = (float*)d_ws;
    float*  c    = ws;                          // 4096*256 f32
    float*  T    = ws + 1048576;                // 4096*256 f32
    ushort* ub   = (ushort*)(ws + 2097152);
    ushort* c_bf = ub;                          // 4096*256 bf16
    ushort* QKb  = ub + 1048576;                // 4096*512 bf16
    ushort* Vt   = ub + 3145728;                // 256*4096 bf16 (V transposed)
    ushort* AO   = ub + 4194304;                // 4096*256 bf16
    ushort* wbf  = ub + 5242880;                // 2*786432 bf16 weights
    float*  bqkv = (float*)(ub + 6815744);      // 2*768 f32
    ushort* Hd   = QKb;                         // 4096*1024 bf16, aliases QKb+Vt+AO

    convert_kernel<<<dim3(3075, 2), 256, 0, stream>>>(WQ, WK, WV, WO, ffn_W1, ffn_W2,
                                                      bQ, bK, bV, wbf, bqkv);
    decorate_kernel<<<NTOK, 256, 0, stream>>>(c_ctx, c_tgt, y_context, exposure_context,
                                              dec_W1, dec_b1, dec_W2, dec_b2, log_kappa, c, c_bf);
    for (int l = 0; l < NL; ++l) {
        ushort* wl = wbf + (size_t)l*786432;
        gemm_bf<<<dim3(12, 64), 256, 0, stream>>>(c_bf, wl, bqkv + l*768, QKb, Vt, NTOK, 768, DD, 4);
        attn_kernel<<<dim3(NTOK/64, NH), 512, 0, stream>>>(QKb, Vt, AO);
        gemm_bf<<<dim3(4, 64),  256, 0, stream>>>(AO,   wl + 196608, bO + l*DD,      T,  nullptr, NTOK, DD, DD, 0);
        ln_kernel<<<NTOK/4, 256, 0, stream>>>(c, T, ln1_g + l*DD, ln1_b + l*DD, c_bf);
        gemm_bf<<<dim3(16, 64), 256, 0, stream>>>(c_bf, wl + 262144, ffn_b1 + l*FFD, Hd, nullptr, NTOK, FFD, DD, 3);
        gemm_bf<<<dim3(4, 64),  256, 0, stream>>>(Hd,   wl + 524288, ffn_b2 + l*DD,  T,  nullptr, NTOK, DD, FFD, 0);
        ln_kernel<<<NTOK/4, 256, 0, stream>>>(c, T, ln2_g + l*DD, ln2_b + l*DD, c_bf);
    }
    out_kernel<<<NT_/4, 256, 0, stream>>>(c, out_W, out_b, exposure_target, out);
}

// Round 7
// 196.977 us; speedup vs baseline: 22.9582x; 1.2466x over previous
//
#include <hip/hip_runtime.h>
#include <hip/hip_bf16.h>
#include <math.h>

#define NC_   3072
#define NT_   1024
#define NTOK  4096
#define DD    256
#define NH    8
#define HDIM  32
#define NL    2
#define FFD   1024

typedef __attribute__((ext_vector_type(8))) short short8;
typedef __attribute__((ext_vector_type(4))) float f32x4;

#if __has_builtin(__builtin_amdgcn_exp2f)
#define EXP2(x) __builtin_amdgcn_exp2f(x)
#else
#define EXP2(x) exp2f(x)
#endif

#define QSCALE 0.25503482964f   // log2(e)/sqrt(32), folded into Q at GEMM epilogue

__device__ inline float bf2f(ushort u) { return __uint_as_float(((unsigned)u) << 16); }
__device__ inline ushort f2bf(float x) {
    __hip_bfloat16 h = __float2bfloat16(x);
    return *reinterpret_cast<ushort*>(&h);
}
__device__ inline void gload16(const void* g, void* l) {
    __builtin_amdgcn_global_load_lds(
        (const __attribute__((address_space(1))) void*)g,
        (__attribute__((address_space(3))) void*)l, 16, 0, 0);
}

// ---------------- weight convert: fp32 [K][N] -> bf16 transposed [N][K], + bQKV concat ----
// packed per-layer (elements): WQKVt[768][256] 0..196607 | WOt 196608 | W1t 262144 | W2t 524288
__global__ __launch_bounds__(256) void convert_kernel(
    const float* __restrict__ WQ, const float* __restrict__ WK,
    const float* __restrict__ WV, const float* __restrict__ WO,
    const float* __restrict__ W1, const float* __restrict__ W2,
    const float* __restrict__ bQ, const float* __restrict__ bK,
    const float* __restrict__ bV, ushort* __restrict__ wbf, float* __restrict__ bqkv)
{
    int l = blockIdx.y;
    int idx = blockIdx.x * 256 + threadIdx.x;
    if (idx >= 786432) {
        int i = idx - 786432;   // < 768 exactly (grid sized 787200/256)
        float bv = (i < 256) ? bQ[l*256 + i]
                 : (i < 512) ? bK[l*256 + (i - 256)]
                             : bV[l*256 + (i - 512)];
        bqkv[l*768 + i] = bv;
        return;
    }
    float v;
    if (idx < 196608) {                 // WQKVt[768][256]
        int n = idx >> 8, k = idx & 255;
        v = (n < 256) ? WQ[(size_t)(l*256 + k)*256 + n]
          : (n < 512) ? WK[(size_t)(l*256 + k)*256 + (n-256)]
                      : WV[(size_t)(l*256 + k)*256 + (n-512)];
    } else if (idx < 262144) {          // WOt[256][256]
        int i = idx - 196608, n = i >> 8, k = i & 255;
        v = WO[(size_t)(l*256 + k)*256 + n];
    } else if (idx < 524288) {          // W1t[1024][256]
        int i = idx - 262144, n = i >> 8, k = i & 255;
        v = W1[(size_t)(l*256 + k)*1024 + n];
    } else {                            // W2t[256][1024]
        int i = idx - 524288, n = i >> 10, k = i & 1023;
        v = W2[(size_t)(l*1024 + k)*256 + n];
    }
    wbf[(size_t)l*786432 + idx] = f2bf(v);
}

// ---------------- outcome-token decorator (f32 out + bf16 copy) ----------------
__global__ __launch_bounds__(256) void decorate_kernel(
    const float* __restrict__ c_ctx, const float* __restrict__ c_tgt,
    const float* __restrict__ y_context, const float* __restrict__ exposure_context,
    const float* __restrict__ dec_W1, const float* __restrict__ dec_b1,
    const float* __restrict__ dec_W2, const float* __restrict__ dec_b2,
    const float* __restrict__ log_kappa, float* __restrict__ c, ushort* __restrict__ cbf)
{
    int row = blockIdx.x, tid = threadIdx.x;
    if (row >= NC_) {
        float v = c_tgt[(size_t)(row-NC_)*DD + tid];
        c[(size_t)row*DD + tid] = v;
        cbf[(size_t)row*DD + tid] = f2bf(v);
        return;
    }
    __shared__ float tv[DD];
    float y = y_context[row];
    tv[tid] = tanhf(y * dec_W1[tid] + dec_b1[tid]);
    __syncthreads();
    float kappa = log1pf(expf(log_kappa[0]));   // softplus
    float e = exposure_context[row];
    float w = e / (e + kappa);
    float acc = 0.f;
    #pragma unroll 16
    for (int k = 0; k < DD; ++k) acc += tv[k] * dec_W2[k*DD + tid];
    float v = c_ctx[(size_t)row*DD + tid] + w * (acc + dec_b2[tid]);
    c[(size_t)row*DD + tid] = v;
    cbf[(size_t)row*DD + tid] = f2bf(v);
}

// ---------------- bf16 MFMA GEMM: C[M][N] = A[M][K] @ Bt[N][K]^T + bias ----------------
// 64x64 tile, BK=64, 4 waves (2x2 of 32x32), global_load_lds w/ pre-swizzled source.
// mode: 0=f32, 1=bf16, 2=bf16 transposed, 3=bf16+relu,
// 4=QKV split: ncol<256 -> Qh head-major [h][m][hd] scaled by QSCALE;
//              256..511 -> Kh head-major at Cv+1048576; >=512 -> Cv2 = Vt transposed.
__global__ __launch_bounds__(256) void gemm_bf(
    const ushort* __restrict__ A, const ushort* __restrict__ Bt,
    const float* __restrict__ bias, void* __restrict__ Cv, void* __restrict__ Cv2,
    int M, int N, int K, int mode)
{
    __shared__ ushort As[64*64];   // [64 m][64 k], XOR-swizzled: byte ^= (row&7)<<4
    __shared__ ushort Bs[64*64];
    int tid = threadIdx.x, lane = tid & 63, w = tid >> 6;
    int wm = w >> 1, wn = w & 1;
    int m0 = blockIdx.y * 64, n0 = blockIdx.x * 64;
    int col = lane & 15, grp = lane >> 4;
    f32x4 acc[2][2] = {};

    for (int k0 = 0; k0 < K; k0 += 64) {
        __syncthreads();
        #pragma unroll
        for (int s = 0; s < 2; ++s) {
            int i = tid + s*256;
            int r = i >> 3, j = i & 7;
            int kb = (j*16) ^ ((r & 7) << 4);    // pre-swizzled source byte offset
            gload16((const char*)(A  + (size_t)(m0 + r)*K + k0) + kb,
                    (char*)As + s*4096 + w*1024);
            gload16((const char*)(Bt + (size_t)(n0 + r)*K + k0) + kb,
                    (char*)Bs + s*4096 + w*1024);
        }
        __syncthreads();
        #pragma unroll
        for (int kk = 0; kk < 64; kk += 32) {
            short8 a[2], b[2];
            #pragma unroll
            for (int f = 0; f < 2; ++f) {
                int ra = wm*32 + f*16 + col;
                a[f] = *(const short8*)((char*)As + ra*128 + (((kk + grp*8)*2) ^ ((ra & 7) << 4)));
                int rb = wn*32 + f*16 + col;
                b[f] = *(const short8*)((char*)Bs + rb*128 + (((kk + grp*8)*2) ^ ((rb & 7) << 4)));
            }
            #pragma unroll
            for (int fm = 0; fm < 2; ++fm)
                #pragma unroll
                for (int fn = 0; fn < 2; ++fn)
                    acc[fm][fn] = __builtin_amdgcn_mfma_f32_16x16x32_bf16(a[fm], b[fn], acc[fm][fn], 0, 0, 0);
        }
    }
    #pragma unroll
    for (int fm = 0; fm < 2; ++fm) {
        #pragma unroll
        for (int fn = 0; fn < 2; ++fn) {
            int ncol = n0 + wn*32 + fn*16 + col;
            int mbase = m0 + wm*32 + fm*16 + grp*4;
            float bs = bias[ncol];
            if (mode == 2 || (mode == 4 && ncol >= 512)) {
                ushort* base = (mode == 2) ? (ushort*)Cv : (ushort*)Cv2 - (size_t)512*M;
                ushort4 u;
                u.x = f2bf(acc[fm][fn][0] + bs); u.y = f2bf(acc[fm][fn][1] + bs);
                u.z = f2bf(acc[fm][fn][2] + bs); u.w = f2bf(acc[fm][fn][3] + bs);
                *(ushort4*)(base + (size_t)ncol*M + mbase) = u;
            } else if (mode == 4) {   // Q (scaled) / K, head-major [h][m][hd]
                int cc = ncol & 255, hh = cc >> 5, hd = cc & 31;
                ushort* base = (ushort*)Cv + ((ncol < 256) ? 0u : 1048576u);
                float sc = (ncol < 256) ? QSCALE : 1.f;
                #pragma unroll
                for (int r = 0; r < 4; ++r)
                    base[((size_t)hh*M + mbase + r)*HDIM + hd] = f2bf((acc[fm][fn][r] + bs) * sc);
            } else {
                #pragma unroll
                for (int r = 0; r < 4; ++r) {
                    float v = acc[fm][fn][r] + bs;
                    if (mode == 3) v = fmaxf(v, 0.f);
                    if (mode == 0) ((float*)Cv)[(size_t)(mbase + r)*N + ncol] = v;
                    else           ((ushort*)Cv)[(size_t)(mbase + r)*N + ncol] = f2bf(v);
                }
            }
        }
    }
}

// ---------------- flash attention: 16 waves, 64 q/block, 128-key tiles, P in-register ----
// grid (NTOK/64, NH), block 1024. Wave w: q-group wq=w&3, key-quarter kh=w>>2 (32 keys).
// QK^T reads K rows PERMUTED (row rA -> key (rA>>2)*8+(rA&3)+4m) so the lane's 8 P
// values are exactly the K=32 B-frag (k=g*8+e) -> PV needs no P-LDS. K rows 80B,
// V^T rows 272B (start-slot distinct per 8 lanes -> <=2-way, free). Reg-staged dbuf,
// 1 barrier/tile. Combine buffer aliases dead K/V LDS. 4-way LSE merge.
// Q pre-scaled by log2(e)/sqrt(32); softmax in exp2 domain; defer-max (THR=8).
__global__ __launch_bounds__(1024, 8) void attn_kernel(
    const ushort* __restrict__ Qh, const ushort* __restrict__ Kh,
    const ushort* __restrict__ Vt, ushort* __restrict__ AO)
{
    __shared__ __align__(16) char smem[37888];   // Ks[2][128*80] | Vs[2][32*272]; then cacc
    __shared__ float cml[16][2][16];
    int tid = threadIdx.x;
    int w = tid >> 6, lane = tid & 63;
    int q = lane & 15, g = lane >> 4;
    int wq = w & 3, kh = w >> 2;
    int h = blockIdx.y;
    int q0 = blockIdx.x * 64;

    // Q B-frag (pre-scaled, head-major): lane holds Q[q0+wq*16+q][g*8..+8]
    short8 bq = *(const short8*)&Qh[((size_t)h*NTOK + q0 + wq*16 + q)*HDIM + g*8];

    f32x4 acc0 = {0.f,0.f,0.f,0.f}, acc1 = {0.f,0.f,0.f,0.f};
    float mC = -INFINITY, lsum = 0.f;
    const f32x4 z = {0.f,0.f,0.f,0.f};
    const int is_tgt = (q0 >= NC_);
    const int nk = is_tgt ? NC_ : NTOK;
    const int nt = nk >> 7;              // 128-key tiles: 24 or 32

    // staging roles: tid<512 stage K (128 rows x 64B), else V (32 rows x 256B)
    const ushort* src0;
    char *dstA, *dstB;
    size_t sstep;
    if (tid < 512) {
        int kk = tid >> 2, sl = tid & 3;
        src0 = Kh + ((size_t)h*NTOK + kk)*HDIM + sl*8;
        dstA = smem + kk*80 + sl*16;
        dstB = dstA + 10240;
        sstep = (size_t)128*HDIM;
    } else {
        int sidx = tid - 512;
        int d = sidx >> 4, sl = sidx & 15;
        src0 = Vt + (size_t)(h*HDIM + d)*NTOK + sl*8;
        dstA = smem + 20480 + d*272 + sl*16;
        dstB = dstA + 8704;
        sstep = 128;
    }
    short8 sreg = {};
    {
        short8 r0 = *(const short8*)src0;            // tile 0
        *(short8*)dstA = r0;
        if (nt > 1) sreg = *(const short8*)(src0 + sstep);   // prefetch tile 1
    }
    asm volatile("s_waitcnt lgkmcnt(0)" ::: "memory");
    __builtin_amdgcn_s_barrier();
    __builtin_amdgcn_sched_barrier(0);

    const int rowp = ((q >> 2) << 3) + (q & 3);      // permuted key-row base
    const char* kb0 = smem + (kh*32 + rowp)*80 + g*16;
    const char* vb0 = smem + 20480 + q*272 + kh*64 + g*16;
    const char* vb1 = vb0 + 16*272;

    for (int t = 0; t < nt; ++t) {
        int cur = t & 1;
        if (t + 1 < nt) {
            *(short8*)(cur ? dstA : dstB) = sreg;    // write next buffer
            if (t + 2 < nt) sreg = *(const short8*)(src0 + (size_t)(t+2)*sstep);
        }
        const char* kb = kb0 + cur*10240;
        short8 ka0 = *(const short8*)(kb);
        short8 ka1 = *(const short8*)(kb + 4*80);
        f32x4 st0 = __builtin_amdgcn_mfma_f32_16x16x32_bf16(ka0, bq, z, 0, 0, 0);
        f32x4 st1 = __builtin_amdgcn_mfma_f32_16x16x32_bf16(ka1, bq, z, 0, 0, 0);
        float mx = fmaxf(fmaxf(fmaxf(st0[0], st0[1]), fmaxf(st0[2], st0[3])),
                         fmaxf(fmaxf(st1[0], st1[1]), fmaxf(st1[2], st1[3])));
        if (__any(mx > mC + 8.f)) {      // deferred rescale (rare); per-q max over g-groups
            float M = mx;
            M = fmaxf(M, __shfl_xor(M, 16, 64));
            M = fmaxf(M, __shfl_xor(M, 32, 64));
            float mCn = fmaxf(mC, M);
            float corr = EXP2(mC - mCn);
            acc0 *= corr; acc1 *= corr; lsum *= corr;
            mC = mCn;
        }
        float p0 = EXP2(st0[0] - mC), p1 = EXP2(st0[1] - mC);
        float p2 = EXP2(st0[2] - mC), p3 = EXP2(st0[3] - mC);
        float p4 = EXP2(st1[0] - mC), p5 = EXP2(st1[1] - mC);
        float p6 = EXP2(st1[2] - mC), p7 = EXP2(st1[3] - mC);
        lsum += ((p0 + p1) + (p2 + p3)) + ((p4 + p5) + (p6 + p7));
        short8 pf;
        pf[0] = (short)f2bf(p0); pf[1] = (short)f2bf(p1);
        pf[2] = (short)f2bf(p2); pf[3] = (short)f2bf(p3);
        pf[4] = (short)f2bf(p4); pf[5] = (short)f2bf(p5);
        pf[6] = (short)f2bf(p6); pf[7] = (short)f2bf(p7);
        short8 va0 = *(const short8*)(vb0 + cur*8704);
        short8 va1 = *(const short8*)(vb1 + cur*8704);
        acc0 = __builtin_amdgcn_mfma_f32_16x16x32_bf16(va0, pf, acc0, 0, 0, 0);
        acc1 = __builtin_amdgcn_mfma_f32_16x16x32_bf16(va1, pf, acc1, 0, 0, 0);
        if (t + 1 < nt) {
            asm volatile("s_waitcnt lgkmcnt(0)" ::: "memory");
            __builtin_amdgcn_s_barrier();
            __builtin_amdgcn_sched_barrier(0);
        }
    }

    if (is_tgt && kh == 0) {   // self-key (structural mask), once per query
        int qg = q0 + wq*16 + q;
        short8 kv = *(const short8*)&Kh[((size_t)h*NTOK + qg)*HDIM + g*8];
        float d8 = 0.f;
        #pragma unroll
        for (int e = 0; e < 8; ++e) d8 += bf2f((ushort)bq[e]) * bf2f((ushort)kv[e]);
        d8 += __shfl_xor(d8, 16, 64);
        d8 += __shfl_xor(d8, 32, 64);    // already log2-scaled (Q pre-scaled)
        float mCn = fmaxf(mC, d8);
        float corr = EXP2(mC - mCn);
        float pp = EXP2(d8 - mCn);
        mC = mCn;
        lsum = lsum*corr + ((g == 0) ? pp : 0.f);
        acc0 *= corr; acc1 *= corr;
        #pragma unroll
        for (int r = 0; r < 4; ++r) {
            acc0[r] += pp * bf2f(Vt[(size_t)(h*HDIM + g*4 + r)*NTOK + qg]);
            acc1[r] += pp * bf2f(Vt[(size_t)(h*HDIM + 16 + g*4 + r)*NTOK + qg]);
        }
    }

    lsum += __shfl_xor(lsum, 16, 64);
    lsum += __shfl_xor(lsum, 32, 64);
    __syncthreads();                      // K/V tiles dead; reuse smem as combine buffer
    float* cacc = (float*)smem;           // [16][32][17]
    #pragma unroll
    for (int r = 0; r < 4; ++r) {
        cacc[(w*32 + g*4 + r)*17 + q]      = acc0[r];
        cacc[(w*32 + 16 + g*4 + r)*17 + q] = acc1[r];
    }
    if (g == 0) { cml[w][0][q] = mC; cml[w][1][q] = lsum; }
    __syncthreads();

    if (w < 4) {   // 4-way LSE merge over key-quarters {w, w+4, w+8, w+12}; q-group w
        float m0_ = cml[w][0][q],    m1_ = cml[w+4][0][q];
        float m2_ = cml[w+8][0][q],  m3_ = cml[w+12][0][q];
        float l0 = cml[w][1][q],     l1 = cml[w+4][1][q];
        float l2 = cml[w+8][1][q],   l3 = cml[w+12][1][q];
        float M = fmaxf(fmaxf(m0_, m1_), fmaxf(m2_, m3_));
        float f0 = EXP2(m0_ - M), f1 = EXP2(m1_ - M), f2 = EXP2(m2_ - M), f3 = EXP2(m3_ - M);
        float inv = 1.f / (l0*f0 + l1*f1 + l2*f2 + l3*f3);
        ushort* dst = AO + (size_t)(q0 + w*16 + q)*DD + h*HDIM;
        ushort4 o0, o1;
        #pragma unroll
        for (int r = 0; r < 4; ++r) {
            int e0 = g*4 + r, e1 = 16 + g*4 + r;
            float O0 = cacc[(w*32+e0)*17+q]*f0 + cacc[((w+4)*32+e0)*17+q]*f1
                     + cacc[((w+8)*32+e0)*17+q]*f2 + cacc[((w+12)*32+e0)*17+q]*f3;
            float O1 = cacc[(w*32+e1)*17+q]*f0 + cacc[((w+4)*32+e1)*17+q]*f1
                     + cacc[((w+8)*32+e1)*17+q]*f2 + cacc[((w+12)*32+e1)*17+q]*f3;
            ((ushort*)&o0)[r] = f2bf(O0 * inv);
            ((ushort*)&o1)[r] = f2bf(O1 * inv);
        }
        *(ushort4*)(dst + g*4) = o0;
        *(ushort4*)(dst + 16 + g*4) = o1;
    }
}

// ---------------- layernorm: c = LN(c + delta)*g + b ; + bf16 copy ----------------
__global__ __launch_bounds__(256) void ln_kernel(
    float* __restrict__ c, const float* __restrict__ delta,
    const float* __restrict__ g, const float* __restrict__ b, ushort* __restrict__ cbf)
{
    int tid = threadIdx.x;
    int wid = tid >> 6, lane = tid & 63;
    int row = blockIdx.x * 4 + wid;
    float4 x  = *(const float4*)&c[(size_t)row*DD + lane*4];
    float4 dl = *(const float4*)&delta[(size_t)row*DD + lane*4];
    x.x += dl.x; x.y += dl.y; x.z += dl.z; x.w += dl.w;
    float s = x.x + x.y + x.z + x.w;
    #pragma unroll
    for (int off = 1; off < 64; off <<= 1) s += __shfl_xor(s, off, 64);
    float mean = s * (1.f/DD);
    float dx = x.x-mean, dy = x.y-mean, dz = x.z-mean, dw = x.w-mean;
    float v = dx*dx + dy*dy + dz*dz + dw*dw;
    #pragma unroll
    for (int off = 1; off < 64; off <<= 1) v += __shfl_xor(v, off, 64);
    float rstd = rsqrtf(v*(1.f/DD) + 1e-5f);
    float4 g4 = *(const float4*)&g[lane*4];
    float4 b4 = *(const float4*)&b[lane*4];
    float4 o;
    o.x = dx*rstd*g4.x + b4.x;
    o.y = dy*rstd*g4.y + b4.y;
    o.z = dz*rstd*g4.z + b4.z;
    o.w = dw*rstd*g4.w + b4.w;
    *(float4*)&c[(size_t)row*DD + lane*4] = o;
    ushort4 u;
    u.x = f2bf(o.x); u.y = f2bf(o.y); u.z = f2bf(o.z); u.w = f2bf(o.w);
    *(ushort4*)&cbf[(size_t)row*DD + lane*4] = u;
}

// ---------------- head: out = exp(c_tgt @ out_W + out_b) * exposure ----------------
__global__ __launch_bounds__(256) void out_kernel(
    const float* __restrict__ c, const float* __restrict__ out_W,
    const float* __restrict__ out_b, const float* __restrict__ exposure_target,
    float* __restrict__ out)
{
    int tid = threadIdx.x;
    int wid = tid >> 6, lane = tid & 63;
    int r = blockIdx.x * 4 + wid;
    float4 cv = *(const float4*)&c[(size_t)(NC_ + r)*DD + lane*4];
    float4 wv = *(const float4*)&out_W[lane*4];
    float s = cv.x*wv.x + cv.y*wv.y + cv.z*wv.z + cv.w*wv.w;
    #pragma unroll
    for (int off = 1; off < 64; off <<= 1) s += __shfl_xor(s, off, 64);
    if (lane == 0) out[r] = expf(s + out_b[0]) * exposure_target[r];
}

extern "C" void kernel_launch(void* const* d_in, const int* in_sizes, int n_in,
                              void* d_out, int out_size, void* d_ws, size_t ws_size,
                              hipStream_t stream) {
    const float* c_ctx            = (const float*)d_in[0];
    const float* c_tgt            = (const float*)d_in[1];
    const float* y_context        = (const float*)d_in[2];
    const float* exposure_context = (const float*)d_in[3];
    const float* exposure_target  = (const float*)d_in[4];
    const float* dec_W1           = (const float*)d_in[5];
    const float* dec_b1           = (const float*)d_in[6];
    const float* dec_W2           = (const float*)d_in[7];
    const float* dec_b2           = (const float*)d_in[8];
    const float* log_kappa        = (const float*)d_in[9];
    const float* WQ               = (const float*)d_in[10];
    const float* bQ               = (const float*)d_in[11];
    const float* WK               = (const float*)d_in[12];
    const float* bK               = (const float*)d_in[13];
    const float* WV               = (const float*)d_in[14];
    const float* bV               = (const float*)d_in[15];
    const float* WO               = (const float*)d_in[16];
    const float* bO               = (const float*)d_in[17];
    const float* ln1_g            = (const float*)d_in[18];
    const float* ln1_b            = (const float*)d_in[19];
    const float* ln2_g            = (const float*)d_in[20];
    const float* ln2_b            = (const float*)d_in[21];
    const float* ffn_W1           = (const float*)d_in[22];
    const float* ffn_b1           = (const float*)d_in[23];
    const float* ffn_W2           = (const float*)d_in[24];
    const float* ffn_b2           = (const float*)d_in[25];
    const float* out_W            = (const float*)d_in[26];
    const float* out_b            = (const float*)d_in[27];
    float* out = (float*)d_out;

    float* ws = (float*)d_ws;
    float*  c    = ws;                          // 4096*256 f32
    float*  T    = ws + 1048576;                // 4096*256 f32
    ushort* ub   = (ushort*)(ws + 2097152);
    ushort* c_bf = ub;                          // 4096*256 bf16
    ushort* Qh   = ub + 1048576;                // [8][4096][32] bf16, pre-scaled
    ushort* Khb  = ub + 2097152;                // [8][4096][32] bf16 (= Qh + 1048576)
    ushort* Vt   = ub + 3145728;                // [256][4096] bf16 (V transposed)
    ushort* AO   = ub + 4194304;                // 4096*256 bf16
    ushort* wbf  = ub + 5242880;                // 2*786432 bf16 weights
    float*  bqkv = (float*)(ub + 6815744);      // 2*768 f32
    ushort* Hd   = Qh;                          // 4096*1024 bf16, aliases Qh..AO (dead then)

    convert_kernel<<<dim3(3075, 2), 256, 0, stream>>>(WQ, WK, WV, WO, ffn_W1, ffn_W2,
                                                      bQ, bK, bV, wbf, bqkv);
    decorate_kernel<<<NTOK, 256, 0, stream>>>(c_ctx, c_tgt, y_context, exposure_context,
                                              dec_W1, dec_b1, dec_W2, dec_b2, log_kappa, c, c_bf);
    for (int l = 0; l < NL; ++l) {
        ushort* wl = wbf + (size_t)l*786432;
        gemm_bf<<<dim3(12, 64), 256, 0, stream>>>(c_bf, wl, bqkv + l*768, Qh, Vt, NTOK, 768, DD, 4);
        attn_kernel<<<dim3(NTOK/64, NH), 1024, 0, stream>>>(Qh, Khb, Vt, AO);
        gemm_bf<<<dim3(4, 64),  256, 0, stream>>>(AO,   wl + 196608, bO + l*DD,      T,  nullptr, NTOK, DD, DD, 0);
        ln_kernel<<<NTOK/4, 256, 0, stream>>>(c, T, ln1_g + l*DD, ln1_b + l*DD, c_bf);
        gemm_bf<<<dim3(16, 64), 256, 0, stream>>>(c_bf, wl + 262144, ffn_b1 + l*FFD, Hd, nullptr, NTOK, FFD, DD, 3);
        gemm_bf<<<dim3(4, 64),  256, 0, stream>>>(Hd,   wl + 524288, ffn_b2 + l*DD,  T,  nullptr, NTOK, DD, FFD, 0);
        ln_kernel<<<NTOK/4, 256, 0, stream>>>(c, T, ln2_g + l*DD, ln2_b + l*DD, c_bf);
    }
    out_kernel<<<NT_/4, 256, 0, stream>>>(c, out_W, out_b, exposure_target, out);
}

// Round 8
// 181.876 us; speedup vs baseline: 24.8643x; 1.0830x over previous
//
#include <hip/hip_runtime.h>
#include <hip/hip_bf16.h>
#include <math.h>

#define NC_   3072
#define NT_   1024
#define NTOK  4096
#define DD    256
#define NH    8
#define HDIM  32
#define NL    2
#define FFD   1024

typedef __attribute__((ext_vector_type(8))) short short8;
typedef __attribute__((ext_vector_type(4))) float f32x4;

#if __has_builtin(__builtin_amdgcn_exp2f)
#define EXP2(x) __builtin_amdgcn_exp2f(x)
#else
#define EXP2(x) exp2f(x)
#endif

#define QSCALE 0.25503482964f   // log2(e)/sqrt(32), folded into Q at GEMM epilogue

__device__ inline float bf2f(ushort u) { return __uint_as_float(((unsigned)u) << 16); }
__device__ inline ushort f2bf(float x) {
    __hip_bfloat16 h = __float2bfloat16(x);
    return *reinterpret_cast<ushort*>(&h);
}
__device__ inline void gload16(const void* g, void* l) {
    __builtin_amdgcn_global_load_lds(
        (const __attribute__((address_space(1))) void*)g,
        (__attribute__((address_space(3))) void*)l, 16, 0, 0);
}

// ---------------- weight convert: fp32 [K][N] -> bf16 transposed [N][K], + bQKV concat ----
// packed per-layer (elements): WQKVt[768][256] | WOt 196608 | W1t 262144 | W2t 524288.
// Shared dec_W2t [256][256] appended at wbf + 2*786432 (converted on l==0 pass only).
__global__ __launch_bounds__(256) void convert_kernel(
    const float* __restrict__ WQ, const float* __restrict__ WK,
    const float* __restrict__ WV, const float* __restrict__ WO,
    const float* __restrict__ W1, const float* __restrict__ W2,
    const float* __restrict__ bQ, const float* __restrict__ bK,
    const float* __restrict__ bV, const float* __restrict__ dW2,
    ushort* __restrict__ wbf, float* __restrict__ bqkv)
{
    int l = blockIdx.y;
    int idx = blockIdx.x * 256 + threadIdx.x;
    if (idx >= 787200) {                // shared dec_W2t (l==0 only)
        if (l != 0) return;
        int i = idx - 787200;           // 0..65535
        int n = i >> 8, k = i & 255;
        wbf[(size_t)2*786432 + i] = f2bf(dW2[(size_t)k*256 + n]);
        return;
    }
    if (idx >= 786432) {
        int i = idx - 786432;           // < 768
        float bv = (i < 256) ? bQ[l*256 + i]
                 : (i < 512) ? bK[l*256 + (i - 256)]
                             : bV[l*256 + (i - 512)];
        bqkv[l*768 + i] = bv;
        return;
    }
    float v;
    if (idx < 196608) {                 // WQKVt[768][256]
        int n = idx >> 8, k = idx & 255;
        v = (n < 256) ? WQ[(size_t)(l*256 + k)*256 + n]
          : (n < 512) ? WK[(size_t)(l*256 + k)*256 + (n-256)]
                      : WV[(size_t)(l*256 + k)*256 + (n-512)];
    } else if (idx < 262144) {          // WOt[256][256]
        int i = idx - 196608, n = i >> 8, k = i & 255;
        v = WO[(size_t)(l*256 + k)*256 + n];
    } else if (idx < 524288) {          // W1t[1024][256]
        int i = idx - 262144, n = i >> 8, k = i & 255;
        v = W1[(size_t)(l*256 + k)*1024 + n];
    } else {                            // W2t[256][1024]
        int i = idx - 524288, n = i >> 10, k = i & 1023;
        v = W2[(size_t)(l*1024 + k)*256 + n];
    }
    wbf[(size_t)l*786432 + idx] = f2bf(v);
}

// ---------------- decorator stage 1: tv[m][k] = tanh(y_all[m]*W1[k]+b1[k]) bf16 ----------------
__global__ __launch_bounds__(256) void tanh_kernel(
    const float* __restrict__ y_context, const float* __restrict__ dec_W1,
    const float* __restrict__ dec_b1, ushort* __restrict__ tv)
{
    size_t base = ((size_t)blockIdx.x * 256 + threadIdx.x) * 4;
    int m = base >> 8, k = base & 255;
    float y = (m < NC_) ? y_context[m] : 0.f;
    ushort4 u;
    u.x = f2bf(tanhf(y * dec_W1[k+0] + dec_b1[k+0]));
    u.y = f2bf(tanhf(y * dec_W1[k+1] + dec_b1[k+1]));
    u.z = f2bf(tanhf(y * dec_W1[k+2] + dec_b1[k+2]));
    u.w = f2bf(tanhf(y * dec_W1[k+3] + dec_b1[k+3]));
    *(ushort4*)&tv[base] = u;
}

// ---------------- bf16 MFMA GEMM: C[M][N] = A[M][K] @ Bt[N][K]^T + bias ----------------
// 64x64 tile, BK=64, 4 waves (2x2 of 32x32), global_load_lds w/ pre-swizzled source.
// mode: 0=f32, 1=bf16, 2=bf16 transposed, 3=bf16+relu,
// 4=QKV split: ncol<256 -> Qh head-major [h][m][hd] scaled by QSCALE;
//              256..511 -> Kh head-major at Cv+1048576; >=512 -> Cv2 = Vt transposed.
// 5=decorator: v = c_all[m][n] + w(m)*(acc+bias); Cv=c f32, Cv2=c_bf bf16;
//              xc=exposure_context, ca=c_ctx, cb=c_tgt, lk=log_kappa.
__global__ __launch_bounds__(256) void gemm_bf(
    const ushort* __restrict__ A, const ushort* __restrict__ Bt,
    const float* __restrict__ bias, void* __restrict__ Cv, void* __restrict__ Cv2,
    int M, int N, int K, int mode,
    const float* __restrict__ xc, const float* __restrict__ ca,
    const float* __restrict__ cb, const float* __restrict__ lk)
{
    __shared__ ushort As[64*64];   // [64 m][64 k], XOR-swizzled: byte ^= (row&7)<<4
    __shared__ ushort Bs[64*64];
    int tid = threadIdx.x, lane = tid & 63, w = tid >> 6;
    int wm = w >> 1, wn = w & 1;
    int m0 = blockIdx.y * 64, n0 = blockIdx.x * 64;
    int col = lane & 15, grp = lane >> 4;
    f32x4 acc[2][2] = {};

    for (int k0 = 0; k0 < K; k0 += 64) {
        __syncthreads();
        #pragma unroll
        for (int s = 0; s < 2; ++s) {
            int i = tid + s*256;
            int r = i >> 3, j = i & 7;
            int kb = (j*16) ^ ((r & 7) << 4);    // pre-swizzled source byte offset
            gload16((const char*)(A  + (size_t)(m0 + r)*K + k0) + kb,
                    (char*)As + s*4096 + w*1024);
            gload16((const char*)(Bt + (size_t)(n0 + r)*K + k0) + kb,
                    (char*)Bs + s*4096 + w*1024);
        }
        __syncthreads();
        #pragma unroll
        for (int kk = 0; kk < 64; kk += 32) {
            short8 a[2], b[2];
            #pragma unroll
            for (int f = 0; f < 2; ++f) {
                int ra = wm*32 + f*16 + col;
                a[f] = *(const short8*)((char*)As + ra*128 + (((kk + grp*8)*2) ^ ((ra & 7) << 4)));
                int rb = wn*32 + f*16 + col;
                b[f] = *(const short8*)((char*)Bs + rb*128 + (((kk + grp*8)*2) ^ ((rb & 7) << 4)));
            }
            #pragma unroll
            for (int fm = 0; fm < 2; ++fm)
                #pragma unroll
                for (int fn = 0; fn < 2; ++fn)
                    acc[fm][fn] = __builtin_amdgcn_mfma_f32_16x16x32_bf16(a[fm], b[fn], acc[fm][fn], 0, 0, 0);
        }
    }
    float kap = (mode == 5) ? log1pf(expf(lk[0])) : 0.f;
    #pragma unroll
    for (int fm = 0; fm < 2; ++fm) {
        #pragma unroll
        for (int fn = 0; fn < 2; ++fn) {
            int ncol = n0 + wn*32 + fn*16 + col;
            int mbase = m0 + wm*32 + fm*16 + grp*4;
            float bs = bias[ncol];
            if (mode == 2 || (mode == 4 && ncol >= 512)) {
                ushort* base = (mode == 2) ? (ushort*)Cv : (ushort*)Cv2 - (size_t)512*M;
                ushort4 u;
                u.x = f2bf(acc[fm][fn][0] + bs); u.y = f2bf(acc[fm][fn][1] + bs);
                u.z = f2bf(acc[fm][fn][2] + bs); u.w = f2bf(acc[fm][fn][3] + bs);
                *(ushort4*)(base + (size_t)ncol*M + mbase) = u;
            } else if (mode == 4) {   // Q (scaled) / K, head-major [h][m][hd]
                int cc = ncol & 255, hh = cc >> 5, hd = cc & 31;
                ushort* base = (ushort*)Cv + ((ncol < 256) ? 0u : 1048576u);
                float sc = (ncol < 256) ? QSCALE : 1.f;
                #pragma unroll
                for (int r = 0; r < 4; ++r)
                    base[((size_t)hh*M + mbase + r)*HDIM + hd] = f2bf((acc[fm][fn][r] + bs) * sc);
            } else if (mode == 5) {   // decorator epilogue
                #pragma unroll
                for (int r = 0; r < 4; ++r) {
                    int m = mbase + r;
                    float basev = (m < NC_) ? ca[(size_t)m*DD + ncol]
                                            : cb[(size_t)(m - NC_)*DD + ncol];
                    float wv = 0.f;
                    if (m < NC_) { float e = xc[m]; wv = e / (e + kap); }
                    float v = basev + wv * (acc[fm][fn][r] + bs);
                    ((float*)Cv)[(size_t)m*DD + ncol] = v;
                    ((ushort*)Cv2)[(size_t)m*DD + ncol] = f2bf(v);
                }
            } else {
                #pragma unroll
                for (int r = 0; r < 4; ++r) {
                    float v = acc[fm][fn][r] + bs;
                    if (mode == 3) v = fmaxf(v, 0.f);
                    if (mode == 0) ((float*)Cv)[(size_t)(mbase + r)*N + ncol] = v;
                    else           ((ushort*)Cv)[(size_t)(mbase + r)*N + ncol] = f2bf(v);
                }
            }
        }
    }
}

// ---------------- flash attention: 16 waves, 64 q/block, 128-key tiles, P in-register ----
// grid (NTOK/64, NH), block 1024. Wave w: q-group wq=w&3, key-quarter kh=w>>2 (32 keys).
// Keys stored at PERMUTED physical rows: key k32 -> row hi*16+q' (q'=((k32>>3)<<2)|(k32&3),
// hi=(k32>>2)&1), so compute reads consecutive physical rows q and 16+q (80B pitch ->
// 2-way banks, free) and the lane's 8 P values land exactly at the K=32 B-frag slots
// (pf[e] = P[key g*8+e][q]) -> PV needs no P-LDS. V^T rows 272B (<=2-way). Reg-staged
// dbuf, 1 barrier/tile, setprio around MFMA pairs. Combine buffer aliases dead K/V LDS.
// Q pre-scaled by log2(e)/sqrt(32); softmax in exp2 domain; defer-max (THR=8).
__global__ __launch_bounds__(1024, 8) void attn_kernel(
    const ushort* __restrict__ Qh, const ushort* __restrict__ Kh,
    const ushort* __restrict__ Vt, ushort* __restrict__ AO)
{
    __shared__ __align__(16) char smem[37888];   // Ks[2][128*80] | Vs[2][32*272]; then cacc
    __shared__ float cml[16][2][16];
    int tid = threadIdx.x;
    int w = tid >> 6, lane = tid & 63;
    int q = lane & 15, g = lane >> 4;
    int wq = w & 3, kh = w >> 2;
    int h = blockIdx.y;
    int q0 = blockIdx.x * 64;

    // Q B-frag (pre-scaled, head-major): lane holds Q[q0+wq*16+q][g*8..+8]
    short8 bq = *(const short8*)&Qh[((size_t)h*NTOK + q0 + wq*16 + q)*HDIM + g*8];

    f32x4 acc0 = {0.f,0.f,0.f,0.f}, acc1 = {0.f,0.f,0.f,0.f};
    float mC = -INFINITY, lsum = 0.f;
    const f32x4 z = {0.f,0.f,0.f,0.f};
    const int is_tgt = (q0 >= NC_);
    const int nk = is_tgt ? NC_ : NTOK;
    const int nt = nk >> 7;              // 128-key tiles: 24 or 32

    // staging roles: tid<512 stage K (128 rows x 64B, permuted rows), else V (32 x 256B)
    const ushort* src0;
    char *dstA, *dstB;
    size_t sstep;
    if (tid < 512) {
        int kk = tid >> 2, sl = tid & 3;
        int k32 = kk & 31, ch = kk >> 5;
        int prow = ch*32 + ((k32 >> 2) & 1)*16 + (((k32 >> 3) << 2) | (k32 & 3));
        src0 = Kh + ((size_t)h*NTOK + kk)*HDIM + sl*8;
        dstA = smem + prow*80 + sl*16;
        dstB = dstA + 10240;
        sstep = (size_t)128*HDIM;
    } else {
        int sidx = tid - 512;
        int d = sidx >> 4, sl = sidx & 15;
        src0 = Vt + (size_t)(h*HDIM + d)*NTOK + sl*8;
        dstA = smem + 20480 + d*272 + sl*16;
        dstB = dstA + 8704;
        sstep = 128;
    }
    short8 sreg = {};
    {
        short8 r0 = *(const short8*)src0;            // tile 0
        *(short8*)dstA = r0;
        if (nt > 1) sreg = *(const short8*)(src0 + sstep);   // prefetch tile 1
    }
    asm volatile("s_waitcnt lgkmcnt(0)" ::: "memory");
    __builtin_amdgcn_s_barrier();
    __builtin_amdgcn_sched_barrier(0);

    const char* kb0 = smem + (kh*32 + q)*80 + g*16;        // physical rows q, 16+q
    const char* vb0 = smem + 20480 + q*272 + kh*64 + g*16;
    const char* vb1 = vb0 + 16*272;

    for (int t = 0; t < nt; ++t) {
        int cur = t & 1;
        if (t + 1 < nt) {
            *(short8*)(cur ? dstA : dstB) = sreg;    // write next buffer
            if (t + 2 < nt) sreg = *(const short8*)(src0 + (size_t)(t+2)*sstep);
        }
        const char* kb = kb0 + cur*10240;
        short8 ka0 = *(const short8*)(kb);
        short8 ka1 = *(const short8*)(kb + 16*80);
        __builtin_amdgcn_s_setprio(1);
        f32x4 st0 = __builtin_amdgcn_mfma_f32_16x16x32_bf16(ka0, bq, z, 0, 0, 0);
        f32x4 st1 = __builtin_amdgcn_mfma_f32_16x16x32_bf16(ka1, bq, z, 0, 0, 0);
        __builtin_amdgcn_s_setprio(0);
        float mx = fmaxf(fmaxf(fmaxf(st0[0], st0[1]), fmaxf(st0[2], st0[3])),
                         fmaxf(fmaxf(st1[0], st1[1]), fmaxf(st1[2], st1[3])));
        if (__any(mx > mC + 8.f)) {      // deferred rescale (rare); per-q max over g-groups
            float M = mx;
            M = fmaxf(M, __shfl_xor(M, 16, 64));
            M = fmaxf(M, __shfl_xor(M, 32, 64));
            float mCn = fmaxf(mC, M);
            float corr = EXP2(mC - mCn);
            acc0 *= corr; acc1 *= corr; lsum *= corr;
            mC = mCn;
        }
        float p0 = EXP2(st0[0] - mC), p1 = EXP2(st0[1] - mC);
        float p2 = EXP2(st0[2] - mC), p3 = EXP2(st0[3] - mC);
        float p4 = EXP2(st1[0] - mC), p5 = EXP2(st1[1] - mC);
        float p6 = EXP2(st1[2] - mC), p7 = EXP2(st1[3] - mC);
        lsum += ((p0 + p1) + (p2 + p3)) + ((p4 + p5) + (p6 + p7));
        short8 pf;
        pf[0] = (short)f2bf(p0); pf[1] = (short)f2bf(p1);
        pf[2] = (short)f2bf(p2); pf[3] = (short)f2bf(p3);
        pf[4] = (short)f2bf(p4); pf[5] = (short)f2bf(p5);
        pf[6] = (short)f2bf(p6); pf[7] = (short)f2bf(p7);
        short8 va0 = *(const short8*)(vb0 + cur*8704);
        short8 va1 = *(const short8*)(vb1 + cur*8704);
        __builtin_amdgcn_s_setprio(1);
        acc0 = __builtin_amdgcn_mfma_f32_16x16x32_bf16(va0, pf, acc0, 0, 0, 0);
        acc1 = __builtin_amdgcn_mfma_f32_16x16x32_bf16(va1, pf, acc1, 0, 0, 0);
        __builtin_amdgcn_s_setprio(0);
        if (t + 1 < nt) {
            asm volatile("s_waitcnt lgkmcnt(0)" ::: "memory");
            __builtin_amdgcn_s_barrier();
            __builtin_amdgcn_sched_barrier(0);
        }
    }

    if (is_tgt && kh == 0) {   // self-key (structural mask), once per query
        int qg = q0 + wq*16 + q;
        short8 kv = *(const short8*)&Kh[((size_t)h*NTOK + qg)*HDIM + g*8];
        float d8 = 0.f;
        #pragma unroll
        for (int e = 0; e < 8; ++e) d8 += bf2f((ushort)bq[e]) * bf2f((ushort)kv[e]);
        d8 += __shfl_xor(d8, 16, 64);
        d8 += __shfl_xor(d8, 32, 64);    // already log2-scaled (Q pre-scaled)
        float mCn = fmaxf(mC, d8);
        float corr = EXP2(mC - mCn);
        float pp = EXP2(d8 - mCn);
        mC = mCn;
        lsum = lsum*corr + ((g == 0) ? pp : 0.f);
        acc0 *= corr; acc1 *= corr;
        #pragma unroll
        for (int r = 0; r < 4; ++r) {
            acc0[r] += pp * bf2f(Vt[(size_t)(h*HDIM + g*4 + r)*NTOK + qg]);
            acc1[r] += pp * bf2f(Vt[(size_t)(h*HDIM + 16 + g*4 + r)*NTOK + qg]);
        }
    }

    lsum += __shfl_xor(lsum, 16, 64);
    lsum += __shfl_xor(lsum, 32, 64);
    __syncthreads();                      // K/V tiles dead; reuse smem as combine buffer
    float* cacc = (float*)smem;           // [16][32][17]
    #pragma unroll
    for (int r = 0; r < 4; ++r) {
        cacc[(w*32 + g*4 + r)*17 + q]      = acc0[r];
        cacc[(w*32 + 16 + g*4 + r)*17 + q] = acc1[r];
    }
    if (g == 0) { cml[w][0][q] = mC; cml[w][1][q] = lsum; }
    __syncthreads();

    if (w < 4) {   // 4-way LSE merge over key-quarters {w, w+4, w+8, w+12}; q-group w
        float m0_ = cml[w][0][q],    m1_ = cml[w+4][0][q];
        float m2_ = cml[w+8][0][q],  m3_ = cml[w+12][0][q];
        float l0 = cml[w][1][q],     l1 = cml[w+4][1][q];
        float l2 = cml[w+8][1][q],   l3 = cml[w+12][1][q];
        float M = fmaxf(fmaxf(m0_, m1_), fmaxf(m2_, m3_));
        float f0 = EXP2(m0_ - M), f1 = EXP2(m1_ - M), f2 = EXP2(m2_ - M), f3 = EXP2(m3_ - M);
        float inv = 1.f / (l0*f0 + l1*f1 + l2*f2 + l3*f3);
        ushort* dst = AO + (size_t)(q0 + w*16 + q)*DD + h*HDIM;
        ushort4 o0, o1;
        #pragma unroll
        for (int r = 0; r < 4; ++r) {
            int e0 = g*4 + r, e1 = 16 + g*4 + r;
            float O0 = cacc[(w*32+e0)*17+q]*f0 + cacc[((w+4)*32+e0)*17+q]*f1
                     + cacc[((w+8)*32+e0)*17+q]*f2 + cacc[((w+12)*32+e0)*17+q]*f3;
            float O1 = cacc[(w*32+e1)*17+q]*f0 + cacc[((w+4)*32+e1)*17+q]*f1
                     + cacc[((w+8)*32+e1)*17+q]*f2 + cacc[((w+12)*32+e1)*17+q]*f3;
            ((ushort*)&o0)[r] = f2bf(O0 * inv);
            ((ushort*)&o1)[r] = f2bf(O1 * inv);
        }
        *(ushort4*)(dst + g*4) = o0;
        *(ushort4*)(dst + 16 + g*4) = o1;
    }
}

// ---------------- layernorm: c = LN(c + delta)*g + b ; + bf16 copy ----------------
__global__ __launch_bounds__(256) void ln_kernel(
    float* __restrict__ c, const float* __restrict__ delta,
    const float* __restrict__ g, const float* __restrict__ b, ushort* __restrict__ cbf)
{
    int tid = threadIdx.x;
    int wid = tid >> 6, lane = tid & 63;
    int row = blockIdx.x * 4 + wid;
    float4 x  = *(const float4*)&c[(size_t)row*DD + lane*4];
    float4 dl = *(const float4*)&delta[(size_t)row*DD + lane*4];
    x.x += dl.x; x.y += dl.y; x.z += dl.z; x.w += dl.w;
    float s = x.x + x.y + x.z + x.w;
    #pragma unroll
    for (int off = 1; off < 64; off <<= 1) s += __shfl_xor(s, off, 64);
    float mean = s * (1.f/DD);
    float dx = x.x-mean, dy = x.y-mean, dz = x.z-mean, dw = x.w-mean;
    float v = dx*dx + dy*dy + dz*dz + dw*dw;
    #pragma unroll
    for (int off = 1; off < 64; off <<= 1) v += __shfl_xor(v, off, 64);
    float rstd = rsqrtf(v*(1.f/DD) + 1e-5f);
    float4 g4 = *(const float4*)&g[lane*4];
    float4 b4 = *(const float4*)&b[lane*4];
    float4 o;
    o.x = dx*rstd*g4.x + b4.x;
    o.y = dy*rstd*g4.y + b4.y;
    o.z = dz*rstd*g4.z + b4.z;
    o.w = dw*rstd*g4.w + b4.w;
    *(float4*)&c[(size_t)row*DD + lane*4] = o;
    ushort4 u;
    u.x = f2bf(o.x); u.y = f2bf(o.y); u.z = f2bf(o.z); u.w = f2bf(o.w);
    *(ushort4*)&cbf[(size_t)row*DD + lane*4] = u;
}

// ---------------- head: out = exp(c_tgt @ out_W + out_b) * exposure ----------------
__global__ __launch_bounds__(256) void out_kernel(
    const float* __restrict__ c, const float* __restrict__ out_W,
    const float* __restrict__ out_b, const float* __restrict__ exposure_target,
    float* __restrict__ out)
{
    int tid = threadIdx.x;
    int wid = tid >> 6, lane = tid & 63;
    int r = blockIdx.x * 4 + wid;
    float4 cv = *(const float4*)&c[(size_t)(NC_ + r)*DD + lane*4];
    float4 wv = *(const float4*)&out_W[lane*4];
    float s = cv.x*wv.x + cv.y*wv.y + cv.z*wv.z + cv.w*wv.w;
    #pragma unroll
    for (int off = 1; off < 64; off <<= 1) s += __shfl_xor(s, off, 64);
    if (lane == 0) out[r] = expf(s + out_b[0]) * exposure_target[r];
}

extern "C" void kernel_launch(void* const* d_in, const int* in_sizes, int n_in,
                              void* d_out, int out_size, void* d_ws, size_t ws_size,
                              hipStream_t stream) {
    const float* c_ctx            = (const float*)d_in[0];
    const float* c_tgt            = (const float*)d_in[1];
    const float* y_context        = (const float*)d_in[2];
    const float* exposure_context = (const float*)d_in[3];
    const float* exposure_target  = (const float*)d_in[4];
    const float* dec_W1           = (const float*)d_in[5];
    const float* dec_b1           = (const float*)d_in[6];
    const float* dec_W2           = (const float*)d_in[7];
    const float* dec_b2           = (const float*)d_in[8];
    const float* log_kappa        = (const float*)d_in[9];
    const float* WQ               = (const float*)d_in[10];
    const float* bQ               = (const float*)d_in[11];
    const float* WK               = (const float*)d_in[12];
    const float* bK               = (const float*)d_in[13];
    const float* WV               = (const float*)d_in[14];
    const float* bV               = (const float*)d_in[15];
    const float* WO               = (const float*)d_in[16];
    const float* bO               = (const float*)d_in[17];
    const float* ln1_g            = (const float*)d_in[18];
    const float* ln1_b            = (const float*)d_in[19];
    const float* ln2_g            = (const float*)d_in[20];
    const float* ln2_b            = (const float*)d_in[21];
    const float* ffn_W1           = (const float*)d_in[22];
    const float* ffn_b1           = (const float*)d_in[23];
    const float* ffn_W2           = (const float*)d_in[24];
    const float* ffn_b2           = (const float*)d_in[25];
    const float* out_W            = (const float*)d_in[26];
    const float* out_b            = (const float*)d_in[27];
    float* out = (float*)d_out;

    float* ws = (float*)d_ws;
    float*  c    = ws;                          // 4096*256 f32
    float*  T    = ws + 1048576;                // 4096*256 f32
    ushort* ub   = (ushort*)(ws + 2097152);
    ushort* c_bf = ub;                          // 4096*256 bf16
    ushort* Qh   = ub + 1048576;                // [8][4096][32] bf16, pre-scaled
    ushort* Khb  = ub + 2097152;                // [8][4096][32] bf16 (= Qh + 1048576)
    ushort* Vt   = ub + 3145728;                // [256][4096] bf16 (V transposed)
    ushort* AO   = ub + 4194304;                // 4096*256 bf16
    ushort* wbf  = ub + 5242880;                // 2*786432 bf16 weights + dec_W2t 65536
    ushort* wdec = wbf + 1572864;               // dec_W2t [256][256]
    float*  bqkv = (float*)(ub + 6881280);      // 2*768 f32
    ushort* tv   = AO;                          // 4096*256 bf16, dead after gemm5
    ushort* Hd   = Qh;                          // 4096*1024 bf16, aliases Qh..AO (dead then)

    convert_kernel<<<dim3(3331, 2), 256, 0, stream>>>(WQ, WK, WV, WO, ffn_W1, ffn_W2,
                                                      bQ, bK, bV, dec_W2, wbf, bqkv);
    tanh_kernel<<<1024, 256, 0, stream>>>(y_context, dec_W1, dec_b1, tv);
    gemm_bf<<<dim3(4, 64), 256, 0, stream>>>(tv, wdec, dec_b2, c, c_bf, NTOK, DD, DD, 5,
                                             exposure_context, c_ctx, c_tgt, log_kappa);
    for (int l = 0; l < NL; ++l) {
        ushort* wl = wbf + (size_t)l*786432;
        gemm_bf<<<dim3(12, 64), 256, 0, stream>>>(c_bf, wl, bqkv + l*768, Qh, Vt, NTOK, 768, DD, 4,
                                                  nullptr, nullptr, nullptr, nullptr);
        attn_kernel<<<dim3(NTOK/64, NH), 1024, 0, stream>>>(Qh, Khb, Vt, AO);
        gemm_bf<<<dim3(4, 64),  256, 0, stream>>>(AO,   wl + 196608, bO + l*DD,      T,  nullptr, NTOK, DD, DD, 0,
                                                  nullptr, nullptr, nullptr, nullptr);
        ln_kernel<<<NTOK/4, 256, 0, stream>>>(c, T, ln1_g + l*DD, ln1_b + l*DD, c_bf);
        gemm_bf<<<dim3(16, 64), 256, 0, stream>>>(c_bf, wl + 262144, ffn_b1 + l*FFD, Hd, nullptr, NTOK, FFD, DD, 3,
                                                  nullptr, nullptr, nullptr, nullptr);
        gemm_bf<<<dim3(4, 64),  256, 0, stream>>>(Hd,   wl + 524288, ffn_b2 + l*DD,  T,  nullptr, NTOK, DD, FFD, 0,
                                                  nullptr, nullptr, nullptr, nullptr);
        ln_kernel<<<NTOK/4, 256, 0, stream>>>(c, T, ln2_g + l*DD, ln2_b + l*DD, c_bf);
    }
    out_kernel<<<NT_/4, 256, 0, stream>>>(c, out_W, out_b, exposure_target, out);
}